// Round 3
// baseline (4347.743 us; speedup 1.0000x reference)
//
#include <hip/hip_runtime.h>

#define BB 128
#define TT 1024
#define DD 256
#define UU 64

// Single-wave LDS ordering fence: same-wave DS ops execute in order at the
// LDS; this forces write retirement (lgkmcnt) + compiler ordering WITHOUT a
// vmcnt drain (keeps the global pot prefetch in flight across steps).
#define WAVE_LDS_FENCE() asm volatile("s_waitcnt lgkmcnt(0)" ::: "memory")

// ---------------- pot = x @ W + b + boundaries ----------------
// v2: x delivered through LDS (vector path) instead of wave-uniform scalar
// loads. Block = 256 threads = 4 waves, owns 64 rows. Per kt (64-d tile):
// stage x[64 rows][64 d] into LDS with coalesced float4 loads (double
// buffered; loads issued BEFORE compute, ds_write after — T14), then each
// wave reads its row back as uniform-address ds_read_b128 broadcasts
// (conflict-free) feeding the identical ascending-d fmaf chain (bit-exact
// vs v1: LDS round-trip preserves bits, FMA order unchanged).
__global__ __launch_bounds__(256, 4) void pot_kernel(
    const float* __restrict__ x, const float* __restrict__ W,
    const float* __restrict__ bvec, const float* __restrict__ left,
    const float* __restrict__ right, const int* __restrict__ lengths,
    float* __restrict__ pot)
{
  const int tid = threadIdx.x;
  const int lane = tid & 63;
  const int w = tid >> 6;
  const int rowblk = (int)blockIdx.x * 64;
  const int wloc = __builtin_amdgcn_readfirstlane(w * 16);   // wave's row offset in block
  const int rbase = rowblk + wloc;                            // wave's global row base

  // 64 rows x 68-float stride (16B-aligned rows; reads are uniform
  // broadcasts so read banks are irrelevant; writes are few).
  __shared__ __align__(16) float xs[2][64][68];

  const int srow = tid >> 4;          // 0..15 (staging row within 16-row pass)
  const int scol = (tid & 15) * 4;    // 0..60 (staging float4 column)

  // prologue: stage kt = 0 into buf 0
  {
    float4 g[4];
#pragma unroll
    for (int q = 0; q < 4; ++q)
      g[q] = *(const float4*)&x[(size_t)(rowblk + q * 16 + srow) * DD + scol];
#pragma unroll
    for (int q = 0; q < 4; ++q)
      *(float4*)&xs[0][q * 16 + srow][scol] = g[q];
  }
  __syncthreads();

  float acc[16];
#pragma unroll
  for (int i = 0; i < 16; ++i) acc[i] = 0.f;

#pragma unroll 1
  for (int kt = 0; kt < 4; ++kt) {
    // issue next tile's global loads early (latency hides under compute)
    float4 g[4];
    if (kt < 3) {
#pragma unroll
      for (int q = 0; q < 4; ++q)
        g[q] = *(const float4*)&x[(size_t)(rowblk + q * 16 + srow) * DD
                                  + (kt + 1) * 64 + scol];
    }

    float wreg[64];
#pragma unroll
    for (int j = 0; j < 64; ++j)
      wreg[j] = W[(size_t)(kt * 64 + j) * UU + lane];

    const int buf = kt & 1;
#pragma unroll
    for (int i = 0; i < 16; ++i) {
      const float4* xr4 = (const float4*)&xs[buf][wloc + i][0];  // uniform addr
#pragma unroll
      for (int jv = 0; jv < 16; ++jv) {
        float4 xv = xr4[jv];
        acc[i] = fmaf(xv.x, wreg[jv * 4 + 0], acc[i]);
        acc[i] = fmaf(xv.y, wreg[jv * 4 + 1], acc[i]);
        acc[i] = fmaf(xv.z, wreg[jv * 4 + 2], acc[i]);
        acc[i] = fmaf(xv.w, wreg[jv * 4 + 3], acc[i]);
      }
    }

    // write next tile into the other buffer (compiler inserts the vmcnt wait)
    if (kt < 3) {
#pragma unroll
      for (int q = 0; q < 4; ++q)
        *(float4*)&xs[buf ^ 1][q * 16 + srow][scol] = g[q];
    }
    __syncthreads();
  }

  const float bb = bvec[lane];
  const float lf = left[lane];
  const float rg = right[lane];
#pragma unroll
  for (int i = 0; i < 16; ++i) {
    int r = rbase + i;
    int bidx = r >> 10;          // r / T
    int t = r & (TT - 1);        // r % T
    int len = lengths[bidx];
    float v = acc[i] + bb;
    if (t == 0) v += lf;
    if (t == len - 1) v += rg;
    pot[(size_t)r * UU + lane] = v;
  }
}

// ---------------- forward + viterbi scans ----------------
// 2*B one-wave blocks: [0,B) forward, [B,2B) viterbi. lane = state u.
//
// Forward: scaled linear domain A = exp(alpha - C*ln2). Raw pot ring is 4
// deep (load at t+7), __expf applied 3 steps after the load (covers L2/LLC
// latency) and the result consumed as pcur 3 steps after that. Same
// elements / same op order as before -> bitwise-identical log_norm.
//
// Viterbi FAST path (fast=1): the recurrence only needs max, not argmax.
// Per step: fmaxf trees (fuse to v_max3_f32, ~1.5 inst/elem) and a
// fire-and-forget store of the step's alpha row to valpha[b][t][:].
// Backpointers are recomputed later, massively parallel, in bp_kernel —
// bit-exact (same f32 adds on same bits, exact max, same first-index
// tie-break). SLOW path (fast=0, small workspace): original in-scan
// argmax + bp store + identity tail.
__global__ __launch_bounds__(64)
__attribute__((amdgpu_waves_per_eu(1, 1))) void scan_kernel(
    const float* __restrict__ pot, const float* __restrict__ trans,
    const int* __restrict__ lengths,
    unsigned char* __restrict__ bp, float* __restrict__ log_norm,
    int* __restrict__ last_tag, float* __restrict__ valpha, int fast)
{
  const int lane = threadIdx.x;
  const int b = blockIdx.x & (BB - 1);
  const bool is_vit = blockIdx.x >= BB;
  const int len = lengths[b];
  const float* potb = pot + (size_t)b * TT * UU;

  __shared__ __align__(16) float sh[2][64];

  if (!is_vit) {
    // ---- scaled linear-domain forward
    float tE[64];
#pragma unroll
    for (int v = 0; v < 64; ++v)
      tE[v] = __expf(trans[v * UU + lane]);

    float A = __expf(potb[lane]);          // t = 0; pot ~ N(0,1), safe
    int C = 0;                             // accumulated exponent (ln2 units)

    // pexp ring (exp'd, feeds t+1..t+3) + raw ring (loads for t+3..t+6).
    // Load issued at step t targets element t+7; it is expf'd at step t+4
    // (3 steps of latency cover) and consumed as pcur at step t+7.
    float pe1 = __expf(potb[UU + lane]);
    float pe2 = __expf(potb[2 * UU + lane]);
    float pe3 = __expf(potb[3 * UU + lane]);
    float pr4 = potb[4 * UU + lane];
    float pr5 = potb[5 * UU + lane];
    float pr6 = potb[6 * UU + lane];
    float pr7 = potb[7 * UU + lane];

#pragma unroll 1
    for (int t = 1; t < len; ++t) {
      const int p = t & 1;
      sh[p][lane] = A;
      float pcur = pe1;
      pe1 = pe2; pe2 = pe3;
      pe3 = __expf(pr4);                   // load is 3 steps old: latency covered
      pr4 = pr5; pr5 = pr6; pr6 = pr7;
      int tp = t + 7 < TT ? t + 7 : TT - 1;
      pr7 = potb[(size_t)tp * UU + lane];
      WAVE_LDS_FENCE();                    // write retired before reads
      const float4* sh4 = (const float4*)sh[p];
      float s0 = 0.f, s1 = 0.f, s2 = 0.f, s3 = 0.f;
#pragma unroll
      for (int vg = 0; vg < 4; ++vg) {
        float4 e0 = sh4[vg * 4 + 0];
        float4 e1 = sh4[vg * 4 + 1];
        float4 e2 = sh4[vg * 4 + 2];
        float4 e3 = sh4[vg * 4 + 3];
        s0 = fmaf(e0.x, tE[vg * 16 + 0], s0);
        s0 = fmaf(e0.y, tE[vg * 16 + 1], s0);
        s0 = fmaf(e0.z, tE[vg * 16 + 2], s0);
        s0 = fmaf(e0.w, tE[vg * 16 + 3], s0);
        s1 = fmaf(e1.x, tE[vg * 16 + 4], s1);
        s1 = fmaf(e1.y, tE[vg * 16 + 5], s1);
        s1 = fmaf(e1.z, tE[vg * 16 + 6], s1);
        s1 = fmaf(e1.w, tE[vg * 16 + 7], s1);
        s2 = fmaf(e2.x, tE[vg * 16 + 8], s2);
        s2 = fmaf(e2.y, tE[vg * 16 + 9], s2);
        s2 = fmaf(e2.z, tE[vg * 16 + 10], s2);
        s2 = fmaf(e2.w, tE[vg * 16 + 11], s2);
        s3 = fmaf(e3.x, tE[vg * 16 + 12], s3);
        s3 = fmaf(e3.y, tE[vg * 16 + 13], s3);
        s3 = fmaf(e3.z, tE[vg * 16 + 14], s3);
        s3 = fmaf(e3.w, tE[vg * 16 + 15], s3);
      }
      float sum = (s0 + s1) + (s2 + s3);
      A = sum * pcur;
      if ((t & 3) == 0) {
        // uniform rescale by lane-0 exponent; all-lane values stay in range
        unsigned ab = __builtin_amdgcn_readfirstlane(__float_as_uint(A));
        int k = (int)((ab >> 23) & 0xffu) - 127;
        C += k;
        A = __builtin_ldexpf(A, -k);
      }
    }
    // log_norm[b] = log(sum_lanes A) + C*ln2
    float e = A;
#pragma unroll
    for (int off = 32; off > 0; off >>= 1)
      e += __shfl_xor(e, off);
    if (lane == 0) log_norm[b] = __logf(e) + (float)C * 0.69314718056f;
  } else {
    float tT[64];
#pragma unroll
    for (int v = 0; v < 64; ++v)
      tT[v] = trans[v * UU + lane];

    float va = potb[lane];

    if (fast) {
      // ---- max-only viterbi scan; alphas stored for parallel bp recompute
      float* vab = valpha + (size_t)b * TT * UU;
      vab[lane] = va;                      // row 0 = pot[b,0,:]
      float pn1 = potb[UU + lane];
      float pn2 = potb[2 * UU + lane];
      float pn3 = potb[3 * UU + lane];
      float pn4 = potb[4 * UU + lane];

#pragma unroll 1
      for (int t = 1; t < len; ++t) {
        const int p = t & 1;
        sh[p][lane] = va;
        float pcur = pn1;
        pn1 = pn2; pn2 = pn3; pn3 = pn4;
        int tp = t + 4 < TT ? t + 4 : TT - 1;
        pn4 = potb[(size_t)tp * UU + lane];
        WAVE_LDS_FENCE();
        const float4* sh4 = (const float4*)sh[p];
        // pure max (exact op, tree shape irrelevant); clang fuses nested
        // fmaxf chains to v_max3_f32 -> ~1.5 inst/elem.
        float m0 = -3.4e38f, m1 = -3.4e38f, m2 = -3.4e38f, m3 = -3.4e38f;
#pragma unroll
        for (int vg = 0; vg < 4; ++vg) {
          float4 e0 = sh4[vg * 4 + 0];
          float4 e1 = sh4[vg * 4 + 1];
          float4 e2 = sh4[vg * 4 + 2];
          float4 e3 = sh4[vg * 4 + 3];
          m0 = fmaxf(fmaxf(fmaxf(fmaxf(e0.x + tT[vg * 16 + 0],
                                       e0.y + tT[vg * 16 + 1]),
                                 e0.z + tT[vg * 16 + 2]),
                           e0.w + tT[vg * 16 + 3]), m0);
          m1 = fmaxf(fmaxf(fmaxf(fmaxf(e1.x + tT[vg * 16 + 4],
                                       e1.y + tT[vg * 16 + 5]),
                                 e1.z + tT[vg * 16 + 6]),
                           e1.w + tT[vg * 16 + 7]), m1);
          m2 = fmaxf(fmaxf(fmaxf(fmaxf(e2.x + tT[vg * 16 + 8],
                                       e2.y + tT[vg * 16 + 9]),
                                 e2.z + tT[vg * 16 + 10]),
                           e2.w + tT[vg * 16 + 11]), m2);
          m3 = fmaxf(fmaxf(fmaxf(fmaxf(e3.x + tT[vg * 16 + 12],
                                       e3.y + tT[vg * 16 + 13]),
                                 e3.z + tT[vg * 16 + 14]),
                           e3.w + tT[vg * 16 + 15]), m3);
        }
        float m = fmaxf(fmaxf(m0, m1), fmaxf(m2, m3));
        va = m + pcur;
        vab[(size_t)t * UU + lane] = va;   // fire-and-forget, off-chain
      }
    } else {
      // ---- original in-scan argmax path (fallback for small workspace)
      float pn1 = potb[UU + lane];
      float pn2 = potb[2 * UU + lane];
      float pn3 = potb[3 * UU + lane];
      unsigned char* bpb = bp + (size_t)b * TT * UU;

#pragma unroll 1
      for (int t = 1; t < len; ++t) {
        const int p = t & 1;
        sh[p][lane] = va;
        float pcur = pn1;
        pn1 = pn2; pn2 = pn3;
        int tp = t + 3 < TT ? t + 3 : TT - 1;
        pn3 = potb[(size_t)tp * UU + lane];
        WAVE_LDS_FENCE();
        const float4* sh4 = (const float4*)sh[p];
        float mc[8];
        int ac[8];
#pragma unroll
        for (int c = 0; c < 8; ++c) {
          float m = -3.4e38f;
          int am = 0;
#pragma unroll
          for (int q = 0; q < 2; ++q) {
            float4 a4 = sh4[c * 2 + q];
            int base = c * 8 + q * 4;
            float s;
            s = a4.x + tT[base + 0]; if (s > m) { m = s; am = base + 0; }
            s = a4.y + tT[base + 1]; if (s > m) { m = s; am = base + 1; }
            s = a4.z + tT[base + 2]; if (s > m) { m = s; am = base + 2; }
            s = a4.w + tT[base + 3]; if (s > m) { m = s; am = base + 3; }
          }
          mc[c] = m; ac[c] = am;
        }
        float m = mc[0]; int am = ac[0];
#pragma unroll
        for (int c = 1; c < 8; ++c) {
          if (mc[c] > m) { m = mc[c]; am = ac[c]; }
        }
        va = m + pcur;
        bpb[(size_t)(t - 1) * UU + lane] = (unsigned char)am;
      }

      // identity backpointers for rows r in [len-1, TT-2]
      {
        const int off = lane * 4;          // 0..252
        const unsigned b0 = (unsigned)(off & 63);
        const unsigned pattern = b0 | ((b0 + 1) << 8) | ((b0 + 2) << 16) | ((b0 + 3) << 24);
#pragma unroll 1
        for (int r0 = len - 1; r0 < TT - 1; r0 += 4) {
          int row = r0 + (off >> 6);
          if (row < TT - 1)
            *(unsigned*)(bpb + (size_t)row * UU + (off & 63)) = pattern;
        }
      }
    }

    // last_tag[b] = argmax over lanes, first-index tie-break (np.argmax)
    float v = va;
    int idx = lane;
#pragma unroll
    for (int off = 32; off > 0; off >>= 1) {
      float vo = __shfl_down(v, off);
      int io = __shfl_down(idx, off);
      if (vo > v || (vo == v && io < idx)) { v = vo; idx = io; }
    }
    if (lane == 0) last_tag[b] = idx;
  }
}

// ---------------- parallel backpointer recompute (fast path) ----------------
// bp[b][r][u] = argmax_v(valpha[b][r][v] + trans[v][u]) for r <= len-2,
// identity for r in [len-1, TT-2]. 128*1023 independent rows, one wave per
// 4 rows. Bit-exact vs the serial scan: identical f32 adds on identical
// stored bits, ascending strict-> preserves np.argmax first-index ties.
__global__ __launch_bounds__(256) void bp_kernel(
    const float* __restrict__ valpha, const float* __restrict__ trans,
    const int* __restrict__ lengths, unsigned char* __restrict__ bp)
{
  const int lane = threadIdx.x & 63;
  const int w = __builtin_amdgcn_readfirstlane((int)(threadIdx.x >> 6));
  const int b = blockIdx.x >> 6;                  // 64 blocks per batch elem
  const int rg = ((int)(blockIdx.x & 63)) * 16 + w * 4;
  const int len = lengths[b];

  float tcol[64];
#pragma unroll
  for (int v = 0; v < 64; ++v)
    tcol[v] = trans[v * UU + lane];

  unsigned char* bpb = bp + (size_t)b * TT * UU;
#pragma unroll
  for (int k = 0; k < 4; ++k) {
    int r = rg + k;
    if (r >= TT - 1) continue;
    if (r >= len - 1) {
      bpb[(size_t)r * UU + lane] = (unsigned char)lane;   // identity rows
    } else {
      // valpha row is wave-uniform -> scalar loads (SGPR operand on the add)
      const float* vr = valpha + ((size_t)b * TT + r) * UU;
      float m = vr[0] + tcol[0];
      int am = 0;
#pragma unroll
      for (int v = 1; v < 64; ++v) {
        float s = vr[v] + tcol[v];
        if (s > m) { m = s; am = v; }
      }
      bpb[(size_t)r * UU + lane] = (unsigned char)am;
    }
  }
}

// ---------------- gold score + backtrack + decode ----------------
__global__ __launch_bounds__(64)
__attribute__((amdgpu_waves_per_eu(1, 1))) void decode_kernel(
    const float* __restrict__ pot, const float* __restrict__ trans,
    const int* __restrict__ tags, const int* __restrict__ lengths,
    const unsigned char* __restrict__ bp, const float* __restrict__ log_norm,
    const int* __restrict__ last_tag, float* __restrict__ score,
    float* __restrict__ dec_out)
{
  const int lane = threadIdx.x;
  const int b = blockIdx.x;
  const int len = lengths[b];
  const float* potb = pot + (size_t)b * TT * UU;
  const int* tagb = tags + (size_t)b * TT;

  // gold path score (unary + binary over valid positions)
  float s = 0.f;
#pragma unroll 1
  for (int i = 0; i < TT / 64; ++i) {
    int t = i * 64 + lane;
    if (t < len) {
      int tg = tagb[t];
      s += potb[(size_t)t * UU + tg];
      if (t > 0) s += trans[tagb[t - 1] * UU + tg];
    }
  }
#pragma unroll
  for (int off = 32; off > 0; off >>= 1)
    s += __shfl_xor(s, off);
  if (lane == 0) score[b] = s - log_norm[b];

  // backtrack: row loads are tag-independent -> prefetch 8 deep; only the
  // __shfl is on the dependent chain.
  __shared__ int sd[TT];
  const unsigned char* bpb = bp + (size_t)b * TT * UU;
  int tag = last_tag[b];
  if (lane == 0) sd[TT - 1] = tag;
#pragma unroll 1
  for (int tg = TT - 2; tg >= 0; tg -= 8) {
    unsigned char rows[8];
#pragma unroll
    for (int k = 0; k < 8; ++k) {
      int t = tg - k;
      rows[k] = (t >= 0) ? bpb[(size_t)t * UU + lane] : (unsigned char)0;
    }
#pragma unroll
    for (int k = 0; k < 8; ++k) {
      int t = tg - k;
      if (t >= 0) {
        int prev = __shfl((int)rows[k], tag);
        if (lane == 0) sd[t] = prev;
        tag = prev;
      }
    }
  }
  __syncthreads();
  float* db = dec_out + (size_t)b * TT;
#pragma unroll 1
  for (int i = 0; i < TT / 64; ++i) {
    int t = i * 64 + lane;
    db[t] = (t < len) ? (float)sd[t] : 0.f;
  }
}

// ---------------- final loss reduction ----------------
__global__ __launch_bounds__(128) void loss_kernel(
    const float* __restrict__ score, float* __restrict__ out)
{
  int tid = threadIdx.x;
  float s = score[tid];
#pragma unroll
  for (int off = 32; off > 0; off >>= 1)
    s += __shfl_xor(s, off);
  __shared__ float partial[2];
  if ((tid & 63) == 0) partial[tid >> 6] = s;
  __syncthreads();
  if (tid == 0) out[0] = -(partial[0] + partial[1]) / (float)BB;
}

extern "C" void kernel_launch(void* const* d_in, const int* in_sizes, int n_in,
                              void* d_out, int out_size, void* d_ws, size_t ws_size,
                              hipStream_t stream)
{
  (void)in_sizes; (void)n_in; (void)out_size;
  const float* x      = (const float*)d_in[0];
  const float* W      = (const float*)d_in[1];
  const float* bvec   = (const float*)d_in[2];
  const float* trans  = (const float*)d_in[3];
  const float* left   = (const float*)d_in[4];
  const float* right  = (const float*)d_in[5];
  const int* tags     = (const int*)d_in[6];
  const int* lengths  = (const int*)d_in[7];

  float* out      = (float*)d_out;
  float* dec_out  = out + 1;                       // [B,T] as float
  float* pot      = out + 1 + (size_t)BB * TT;     // [B,T,U]

  const size_t bpB = (size_t)BB * TT * UU;         // 8 MiB backpointers
  const size_t vaB = (size_t)BB * TT * UU * 4;     // 32 MiB viterbi alphas
  const int fast = (ws_size >= bpB + vaB + 4096) ? 1 : 0;

  unsigned char* bp = (unsigned char*)d_ws;
  float* valpha     = (float*)((char*)d_ws + bpB);
  char* tail        = (char*)d_ws + bpB + (fast ? vaB : 0);
  float* log_norm   = (float*)tail;
  int*   last_tag   = (int*)(log_norm + BB);
  float* score      = (float*)(last_tag + BB);

  pot_kernel<<<(BB * TT) / 64, 256, 0, stream>>>(x, W, bvec, left, right, lengths, pot);
  scan_kernel<<<2 * BB, 64, 0, stream>>>(pot, trans, lengths, bp, log_norm, last_tag, valpha, fast);
  if (fast)
    bp_kernel<<<BB * 64, 256, 0, stream>>>(valpha, trans, lengths, bp);
  decode_kernel<<<BB, 64, 0, stream>>>(pot, trans, tags, lengths, bp, log_norm, last_tag, score, dec_out);
  loss_kernel<<<1, 128, 0, stream>>>(score, out);
}

// Round 4
// 2845.132 us; speedup vs baseline: 1.5281x; 1.5281x over previous
//
#include <hip/hip_runtime.h>

#define BB 128
#define TT 1024
#define DD 256
#define UU 64

// Single-wave LDS ordering fence: same-wave DS ops execute in order at the
// LDS; this forces write retirement (lgkmcnt) + compiler ordering WITHOUT a
// vmcnt drain (keeps the global pot prefetch in flight across steps).
#define WAVE_LDS_FENCE() asm volatile("s_waitcnt lgkmcnt(0)" ::: "memory")

// ---------------- pot = x @ W + b + boundaries ----------------
// v3: x delivered through LDS (vector path; fixes round-2's scalar-pipe
// bottleneck) with W register working set CHUNKED to 16 (fixes round-3's
// 64-VGPR spill catastrophe: launch_bounds(256,4) + wreg[64] forced scratch
// spills -> 12.5 GB HBM traffic). No occupancy attribute: ~80 live VGPRs
// gives 4 waves/SIMD naturally.
// Bit-exact vs the verified kernel: per output element the FMA chain is
// d = kt*64 + jc*16 + j, ascending 0..255 — identical order; the LDS
// round-trip of x preserves bits; +b, +left, +right order unchanged.
__global__ __launch_bounds__(256) void pot_kernel(
    const float* __restrict__ x, const float* __restrict__ W,
    const float* __restrict__ bvec, const float* __restrict__ left,
    const float* __restrict__ right, const int* __restrict__ lengths,
    float* __restrict__ pot)
{
  const int tid = threadIdx.x;
  const int lane = tid & 63;
  const int w = tid >> 6;
  const int rowblk = (int)blockIdx.x * 64;
  const int wloc = __builtin_amdgcn_readfirstlane(w * 16);   // wave's row offset in block
  const int rbase = rowblk + wloc;                            // wave's global row base

  // 64 rows x 68-float stride (16B-aligned rows; compute reads are
  // wave-uniform broadcasts so read banks are irrelevant).
  __shared__ __align__(16) float xs[2][64][68];

  const int srow = tid >> 4;          // 0..15 (staging row within 16-row pass)
  const int scol = (tid & 15) * 4;    // 0..60 (staging float4 column)

  // prologue: stage kt = 0 into buf 0
  {
    float4 g[4];
#pragma unroll
    for (int q = 0; q < 4; ++q)
      g[q] = *(const float4*)&x[(size_t)(rowblk + q * 16 + srow) * DD + scol];
#pragma unroll
    for (int q = 0; q < 4; ++q)
      *(float4*)&xs[0][q * 16 + srow][scol] = g[q];
  }
  __syncthreads();

  float acc[16];
#pragma unroll
  for (int i = 0; i < 16; ++i) acc[i] = 0.f;

#pragma unroll 1
  for (int kt = 0; kt < 4; ++kt) {
    // issue next tile's global loads early (latency hides under compute)
    float4 g[4];
    if (kt < 3) {
#pragma unroll
      for (int q = 0; q < 4; ++q)
        g[q] = *(const float4*)&x[(size_t)(rowblk + q * 16 + srow) * DD
                                  + (kt + 1) * 64 + scol];
    }

    const int buf = kt & 1;
    // W working set chunked to 16 regs: jc walks 4 sub-tiles of 16 d-values.
#pragma unroll
    for (int jc = 0; jc < 4; ++jc) {
      float wreg16[16];
#pragma unroll
      for (int j = 0; j < 16; ++j)
        wreg16[j] = W[(size_t)(kt * 64 + jc * 16 + j) * UU + lane];

#pragma unroll
      for (int i = 0; i < 16; ++i) {
        const float4* xr4 = (const float4*)&xs[buf][wloc + i][jc * 16];  // uniform addr
#pragma unroll
        for (int jv = 0; jv < 4; ++jv) {
          float4 xv = xr4[jv];
          acc[i] = fmaf(xv.x, wreg16[jv * 4 + 0], acc[i]);
          acc[i] = fmaf(xv.y, wreg16[jv * 4 + 1], acc[i]);
          acc[i] = fmaf(xv.z, wreg16[jv * 4 + 2], acc[i]);
          acc[i] = fmaf(xv.w, wreg16[jv * 4 + 3], acc[i]);
        }
      }
    }

    // write next tile into the other buffer (compiler inserts the vmcnt wait)
    if (kt < 3) {
#pragma unroll
      for (int q = 0; q < 4; ++q)
        *(float4*)&xs[buf ^ 1][q * 16 + srow][scol] = g[q];
    }
    __syncthreads();
  }

  const float bb = bvec[lane];
  const float lf = left[lane];
  const float rg = right[lane];
#pragma unroll
  for (int i = 0; i < 16; ++i) {
    int r = rbase + i;
    int bidx = r >> 10;          // r / T
    int t = r & (TT - 1);        // r % T
    int len = lengths[bidx];
    float v = acc[i] + bb;
    if (t == 0) v += lf;
    if (t == len - 1) v += rg;
    pot[(size_t)r * UU + lane] = v;
  }
}

// ---------------- forward + viterbi scans ----------------
// 2*B one-wave blocks: [0,B) forward, [B,2B) viterbi. lane = state u.
//
// Forward: scaled linear domain A = exp(alpha - C*ln2). Raw pot ring is 4
// deep (load at t+7), __expf applied 3 steps after the load (covers L2/LLC
// latency) and the result consumed as pcur 3 steps after that. Same
// elements / same op order as before -> bitwise-identical log_norm.
//
// Viterbi FAST path (fast=1): the recurrence only needs max, not argmax.
// Per step: fmaxf trees (fuse to v_max3_f32, ~1.5 inst/elem) and a
// fire-and-forget store of the step's alpha row to valpha[b][t][:].
// Backpointers are recomputed later, massively parallel, in bp_kernel —
// bit-exact (same f32 adds on same bits, exact max, same first-index
// tie-break). SLOW path (fast=0, small workspace): original in-scan
// argmax + bp store + identity tail.
__global__ __launch_bounds__(64)
__attribute__((amdgpu_waves_per_eu(1, 1))) void scan_kernel(
    const float* __restrict__ pot, const float* __restrict__ trans,
    const int* __restrict__ lengths,
    unsigned char* __restrict__ bp, float* __restrict__ log_norm,
    int* __restrict__ last_tag, float* __restrict__ valpha, int fast)
{
  const int lane = threadIdx.x;
  const int b = blockIdx.x & (BB - 1);
  const bool is_vit = blockIdx.x >= BB;
  const int len = lengths[b];
  const float* potb = pot + (size_t)b * TT * UU;

  __shared__ __align__(16) float sh[2][64];

  if (!is_vit) {
    // ---- scaled linear-domain forward
    float tE[64];
#pragma unroll
    for (int v = 0; v < 64; ++v)
      tE[v] = __expf(trans[v * UU + lane]);

    float A = __expf(potb[lane]);          // t = 0; pot ~ N(0,1), safe
    int C = 0;                             // accumulated exponent (ln2 units)

    // pexp ring (exp'd, feeds t+1..t+3) + raw ring (loads for t+3..t+6).
    // Load issued at step t targets element t+7; it is expf'd at step t+4
    // (3 steps of latency cover) and consumed as pcur at step t+7.
    float pe1 = __expf(potb[UU + lane]);
    float pe2 = __expf(potb[2 * UU + lane]);
    float pe3 = __expf(potb[3 * UU + lane]);
    float pr4 = potb[4 * UU + lane];
    float pr5 = potb[5 * UU + lane];
    float pr6 = potb[6 * UU + lane];
    float pr7 = potb[7 * UU + lane];

#pragma unroll 1
    for (int t = 1; t < len; ++t) {
      const int p = t & 1;
      sh[p][lane] = A;
      float pcur = pe1;
      pe1 = pe2; pe2 = pe3;
      pe3 = __expf(pr4);                   // load is 3 steps old: latency covered
      pr4 = pr5; pr5 = pr6; pr6 = pr7;
      int tp = t + 7 < TT ? t + 7 : TT - 1;
      pr7 = potb[(size_t)tp * UU + lane];
      WAVE_LDS_FENCE();                    // write retired before reads
      const float4* sh4 = (const float4*)sh[p];
      float s0 = 0.f, s1 = 0.f, s2 = 0.f, s3 = 0.f;
#pragma unroll
      for (int vg = 0; vg < 4; ++vg) {
        float4 e0 = sh4[vg * 4 + 0];
        float4 e1 = sh4[vg * 4 + 1];
        float4 e2 = sh4[vg * 4 + 2];
        float4 e3 = sh4[vg * 4 + 3];
        s0 = fmaf(e0.x, tE[vg * 16 + 0], s0);
        s0 = fmaf(e0.y, tE[vg * 16 + 1], s0);
        s0 = fmaf(e0.z, tE[vg * 16 + 2], s0);
        s0 = fmaf(e0.w, tE[vg * 16 + 3], s0);
        s1 = fmaf(e1.x, tE[vg * 16 + 4], s1);
        s1 = fmaf(e1.y, tE[vg * 16 + 5], s1);
        s1 = fmaf(e1.z, tE[vg * 16 + 6], s1);
        s1 = fmaf(e1.w, tE[vg * 16 + 7], s1);
        s2 = fmaf(e2.x, tE[vg * 16 + 8], s2);
        s2 = fmaf(e2.y, tE[vg * 16 + 9], s2);
        s2 = fmaf(e2.z, tE[vg * 16 + 10], s2);
        s2 = fmaf(e2.w, tE[vg * 16 + 11], s2);
        s3 = fmaf(e3.x, tE[vg * 16 + 12], s3);
        s3 = fmaf(e3.y, tE[vg * 16 + 13], s3);
        s3 = fmaf(e3.z, tE[vg * 16 + 14], s3);
        s3 = fmaf(e3.w, tE[vg * 16 + 15], s3);
      }
      float sum = (s0 + s1) + (s2 + s3);
      A = sum * pcur;
      if ((t & 3) == 0) {
        // uniform rescale by lane-0 exponent; all-lane values stay in range
        unsigned ab = __builtin_amdgcn_readfirstlane(__float_as_uint(A));
        int k = (int)((ab >> 23) & 0xffu) - 127;
        C += k;
        A = __builtin_ldexpf(A, -k);
      }
    }
    // log_norm[b] = log(sum_lanes A) + C*ln2
    float e = A;
#pragma unroll
    for (int off = 32; off > 0; off >>= 1)
      e += __shfl_xor(e, off);
    if (lane == 0) log_norm[b] = __logf(e) + (float)C * 0.69314718056f;
  } else {
    float tT[64];
#pragma unroll
    for (int v = 0; v < 64; ++v)
      tT[v] = trans[v * UU + lane];

    float va = potb[lane];

    if (fast) {
      // ---- max-only viterbi scan; alphas stored for parallel bp recompute
      float* vab = valpha + (size_t)b * TT * UU;
      vab[lane] = va;                      // row 0 = pot[b,0,:]
      float pn1 = potb[UU + lane];
      float pn2 = potb[2 * UU + lane];
      float pn3 = potb[3 * UU + lane];
      float pn4 = potb[4 * UU + lane];

#pragma unroll 1
      for (int t = 1; t < len; ++t) {
        const int p = t & 1;
        sh[p][lane] = va;
        float pcur = pn1;
        pn1 = pn2; pn2 = pn3; pn3 = pn4;
        int tp = t + 4 < TT ? t + 4 : TT - 1;
        pn4 = potb[(size_t)tp * UU + lane];
        WAVE_LDS_FENCE();
        const float4* sh4 = (const float4*)sh[p];
        // pure max (exact op, tree shape irrelevant); clang fuses nested
        // fmaxf chains to v_max3_f32 -> ~1.5 inst/elem.
        float m0 = -3.4e38f, m1 = -3.4e38f, m2 = -3.4e38f, m3 = -3.4e38f;
#pragma unroll
        for (int vg = 0; vg < 4; ++vg) {
          float4 e0 = sh4[vg * 4 + 0];
          float4 e1 = sh4[vg * 4 + 1];
          float4 e2 = sh4[vg * 4 + 2];
          float4 e3 = sh4[vg * 4 + 3];
          m0 = fmaxf(fmaxf(fmaxf(fmaxf(e0.x + tT[vg * 16 + 0],
                                       e0.y + tT[vg * 16 + 1]),
                                 e0.z + tT[vg * 16 + 2]),
                           e0.w + tT[vg * 16 + 3]), m0);
          m1 = fmaxf(fmaxf(fmaxf(fmaxf(e1.x + tT[vg * 16 + 4],
                                       e1.y + tT[vg * 16 + 5]),
                                 e1.z + tT[vg * 16 + 6]),
                           e1.w + tT[vg * 16 + 7]), m1);
          m2 = fmaxf(fmaxf(fmaxf(fmaxf(e2.x + tT[vg * 16 + 8],
                                       e2.y + tT[vg * 16 + 9]),
                                 e2.z + tT[vg * 16 + 10]),
                           e2.w + tT[vg * 16 + 11]), m2);
          m3 = fmaxf(fmaxf(fmaxf(fmaxf(e3.x + tT[vg * 16 + 12],
                                       e3.y + tT[vg * 16 + 13]),
                                 e3.z + tT[vg * 16 + 14]),
                           e3.w + tT[vg * 16 + 15]), m3);
        }
        float m = fmaxf(fmaxf(m0, m1), fmaxf(m2, m3));
        va = m + pcur;
        vab[(size_t)t * UU + lane] = va;   // fire-and-forget, off-chain
      }
    } else {
      // ---- original in-scan argmax path (fallback for small workspace)
      float pn1 = potb[UU + lane];
      float pn2 = potb[2 * UU + lane];
      float pn3 = potb[3 * UU + lane];
      unsigned char* bpb = bp + (size_t)b * TT * UU;

#pragma unroll 1
      for (int t = 1; t < len; ++t) {
        const int p = t & 1;
        sh[p][lane] = va;
        float pcur = pn1;
        pn1 = pn2; pn2 = pn3;
        int tp = t + 3 < TT ? t + 3 : TT - 1;
        pn3 = potb[(size_t)tp * UU + lane];
        WAVE_LDS_FENCE();
        const float4* sh4 = (const float4*)sh[p];
        float mc[8];
        int ac[8];
#pragma unroll
        for (int c = 0; c < 8; ++c) {
          float m = -3.4e38f;
          int am = 0;
#pragma unroll
          for (int q = 0; q < 2; ++q) {
            float4 a4 = sh4[c * 2 + q];
            int base = c * 8 + q * 4;
            float s;
            s = a4.x + tT[base + 0]; if (s > m) { m = s; am = base + 0; }
            s = a4.y + tT[base + 1]; if (s > m) { m = s; am = base + 1; }
            s = a4.z + tT[base + 2]; if (s > m) { m = s; am = base + 2; }
            s = a4.w + tT[base + 3]; if (s > m) { m = s; am = base + 3; }
          }
          mc[c] = m; ac[c] = am;
        }
        float m = mc[0]; int am = ac[0];
#pragma unroll
        for (int c = 1; c < 8; ++c) {
          if (mc[c] > m) { m = mc[c]; am = ac[c]; }
        }
        va = m + pcur;
        bpb[(size_t)(t - 1) * UU + lane] = (unsigned char)am;
      }

      // identity backpointers for rows r in [len-1, TT-2]
      {
        const int off = lane * 4;          // 0..252
        const unsigned b0 = (unsigned)(off & 63);
        const unsigned pattern = b0 | ((b0 + 1) << 8) | ((b0 + 2) << 16) | ((b0 + 3) << 24);
#pragma unroll 1
        for (int r0 = len - 1; r0 < TT - 1; r0 += 4) {
          int row = r0 + (off >> 6);
          if (row < TT - 1)
            *(unsigned*)(bpb + (size_t)row * UU + (off & 63)) = pattern;
        }
      }
    }

    // last_tag[b] = argmax over lanes, first-index tie-break (np.argmax)
    float v = va;
    int idx = lane;
#pragma unroll
    for (int off = 32; off > 0; off >>= 1) {
      float vo = __shfl_down(v, off);
      int io = __shfl_down(idx, off);
      if (vo > v || (vo == v && io < idx)) { v = vo; idx = io; }
    }
    if (lane == 0) last_tag[b] = idx;
  }
}

// ---------------- parallel backpointer recompute (fast path) ----------------
// bp[b][r][u] = argmax_v(valpha[b][r][v] + trans[v][u]) for r <= len-2,
// identity for r in [len-1, TT-2]. 128*1023 independent rows, one wave per
// 4 rows. Bit-exact vs the serial scan: identical f32 adds on identical
// stored bits, ascending strict-> preserves np.argmax first-index ties.
__global__ __launch_bounds__(256) void bp_kernel(
    const float* __restrict__ valpha, const float* __restrict__ trans,
    const int* __restrict__ lengths, unsigned char* __restrict__ bp)
{
  const int lane = threadIdx.x & 63;
  const int w = __builtin_amdgcn_readfirstlane((int)(threadIdx.x >> 6));
  const int b = blockIdx.x >> 6;                  // 64 blocks per batch elem
  const int rg = ((int)(blockIdx.x & 63)) * 16 + w * 4;
  const int len = lengths[b];

  float tcol[64];
#pragma unroll
  for (int v = 0; v < 64; ++v)
    tcol[v] = trans[v * UU + lane];

  unsigned char* bpb = bp + (size_t)b * TT * UU;
#pragma unroll
  for (int k = 0; k < 4; ++k) {
    int r = rg + k;
    if (r >= TT - 1) continue;
    if (r >= len - 1) {
      bpb[(size_t)r * UU + lane] = (unsigned char)lane;   // identity rows
    } else {
      // valpha row is wave-uniform -> scalar loads (SGPR operand on the add)
      const float* vr = valpha + ((size_t)b * TT + r) * UU;
      float m = vr[0] + tcol[0];
      int am = 0;
#pragma unroll
      for (int v = 1; v < 64; ++v) {
        float s = vr[v] + tcol[v];
        if (s > m) { m = s; am = v; }
      }
      bpb[(size_t)r * UU + lane] = (unsigned char)am;
    }
  }
}

// ---------------- gold score + backtrack + decode ----------------
__global__ __launch_bounds__(64)
__attribute__((amdgpu_waves_per_eu(1, 1))) void decode_kernel(
    const float* __restrict__ pot, const float* __restrict__ trans,
    const int* __restrict__ tags, const int* __restrict__ lengths,
    const unsigned char* __restrict__ bp, const float* __restrict__ log_norm,
    const int* __restrict__ last_tag, float* __restrict__ score,
    float* __restrict__ dec_out)
{
  const int lane = threadIdx.x;
  const int b = blockIdx.x;
  const int len = lengths[b];
  const float* potb = pot + (size_t)b * TT * UU;
  const int* tagb = tags + (size_t)b * TT;

  // gold path score (unary + binary over valid positions)
  float s = 0.f;
#pragma unroll 1
  for (int i = 0; i < TT / 64; ++i) {
    int t = i * 64 + lane;
    if (t < len) {
      int tg = tagb[t];
      s += potb[(size_t)t * UU + tg];
      if (t > 0) s += trans[tagb[t - 1] * UU + tg];
    }
  }
#pragma unroll
  for (int off = 32; off > 0; off >>= 1)
    s += __shfl_xor(s, off);
  if (lane == 0) score[b] = s - log_norm[b];

  // backtrack: row loads are tag-independent -> prefetch 8 deep; only the
  // __shfl is on the dependent chain.
  __shared__ int sd[TT];
  const unsigned char* bpb = bp + (size_t)b * TT * UU;
  int tag = last_tag[b];
  if (lane == 0) sd[TT - 1] = tag;
#pragma unroll 1
  for (int tg = TT - 2; tg >= 0; tg -= 8) {
    unsigned char rows[8];
#pragma unroll
    for (int k = 0; k < 8; ++k) {
      int t = tg - k;
      rows[k] = (t >= 0) ? bpb[(size_t)t * UU + lane] : (unsigned char)0;
    }
#pragma unroll
    for (int k = 0; k < 8; ++k) {
      int t = tg - k;
      if (t >= 0) {
        int prev = __shfl((int)rows[k], tag);
        if (lane == 0) sd[t] = prev;
        tag = prev;
      }
    }
  }
  __syncthreads();
  float* db = dec_out + (size_t)b * TT;
#pragma unroll 1
  for (int i = 0; i < TT / 64; ++i) {
    int t = i * 64 + lane;
    db[t] = (t < len) ? (float)sd[t] : 0.f;
  }
}

// ---------------- final loss reduction ----------------
__global__ __launch_bounds__(128) void loss_kernel(
    const float* __restrict__ score, float* __restrict__ out)
{
  int tid = threadIdx.x;
  float s = score[tid];
#pragma unroll
  for (int off = 32; off > 0; off >>= 1)
    s += __shfl_xor(s, off);
  __shared__ float partial[2];
  if ((tid & 63) == 0) partial[tid >> 6] = s;
  __syncthreads();
  if (tid == 0) out[0] = -(partial[0] + partial[1]) / (float)BB;
}

extern "C" void kernel_launch(void* const* d_in, const int* in_sizes, int n_in,
                              void* d_out, int out_size, void* d_ws, size_t ws_size,
                              hipStream_t stream)
{
  (void)in_sizes; (void)n_in; (void)out_size;
  const float* x      = (const float*)d_in[0];
  const float* W      = (const float*)d_in[1];
  const float* bvec   = (const float*)d_in[2];
  const float* trans  = (const float*)d_in[3];
  const float* left   = (const float*)d_in[4];
  const float* right  = (const float*)d_in[5];
  const int* tags     = (const int*)d_in[6];
  const int* lengths  = (const int*)d_in[7];

  float* out      = (float*)d_out;
  float* dec_out  = out + 1;                       // [B,T] as float
  float* pot      = out + 1 + (size_t)BB * TT;     // [B,T,U]

  const size_t bpB = (size_t)BB * TT * UU;         // 8 MiB backpointers
  const size_t vaB = (size_t)BB * TT * UU * 4;     // 32 MiB viterbi alphas
  const int fast = (ws_size >= bpB + vaB + 4096) ? 1 : 0;

  unsigned char* bp = (unsigned char*)d_ws;
  float* valpha     = (float*)((char*)d_ws + bpB);
  char* tail        = (char*)d_ws + bpB + (fast ? vaB : 0);
  float* log_norm   = (float*)tail;
  int*   last_tag   = (int*)(log_norm + BB);
  float* score      = (float*)(last_tag + BB);

  pot_kernel<<<(BB * TT) / 64, 256, 0, stream>>>(x, W, bvec, left, right, lengths, pot);
  scan_kernel<<<2 * BB, 64, 0, stream>>>(pot, trans, lengths, bp, log_norm, last_tag, valpha, fast);
  if (fast)
    bp_kernel<<<BB * 64, 256, 0, stream>>>(valpha, trans, lengths, bp);
  decode_kernel<<<BB, 64, 0, stream>>>(pot, trans, tags, lengths, bp, log_norm, last_tag, score, dec_out);
  loss_kernel<<<1, 128, 0, stream>>>(score, out);
}

// Round 5
// 869.423 us; speedup vs baseline: 5.0007x; 3.2724x over previous
//
#include <hip/hip_runtime.h>

#define BB 128
#define TT 1024
#define DD 256
#define UU 64

// Single-wave LDS ordering fence: same-wave DS ops execute in order at the
// LDS; this forces write retirement (lgkmcnt) + compiler ordering WITHOUT a
// vmcnt drain (keeps the global pot prefetch in flight across steps).
#define WAVE_LDS_FENCE() asm volatile("s_waitcnt lgkmcnt(0)" ::: "memory")

// ---------------- pot = x @ W + b + boundaries ----------------
// v4: round-0 register structure (wreg[64] + acc[16], 88 VGPR, no spill)
// with x delivered HBM -> LDS via global_load_lds DMA (width 16): staging
// uses ZERO data registers, so the round-3/4 spill storms (reg-staged LDS
// + unrolled W chunks -> live set > 256 VGPR -> GBs of scratch traffic)
// cannot recur. LDS layout is linear [64][64] (global_load_lds writes
// wave-uniform base + lane*16; no padding allowed). Compute reads are
// wave-uniform ds_read_b128 broadcasts - banking irrelevant.
// Bit-exact: x bits round-trip LDS unchanged; FMA chain per output is
// d = kt*64 + jv*4 + k ascending 0..255, identical to the verified kernel.
__global__ __launch_bounds__(256) void pot_kernel(
    const float* __restrict__ x, const float* __restrict__ W,
    const float* __restrict__ bvec, const float* __restrict__ left,
    const float* __restrict__ right, const int* __restrict__ lengths,
    float* __restrict__ pot)
{
  const int tid = threadIdx.x;
  const int lane = tid & 63;
  const int w = tid >> 6;
  const int rowblk = (int)blockIdx.x * 64;
  const int wloc = __builtin_amdgcn_readfirstlane(w * 16);  // wave's rows: wloc..wloc+15
  const int rbase = rowblk + wloc;

  // linear, unpadded: required by global_load_lds lane ordering
  __shared__ __align__(16) float xs[2][64][64];

  // Each wave stages its own 16 rows: 4 DMA instructions x (64 lanes x 16 B
  // = 1 KB = 4 rows of 256 B). Lane l covers row +(l>>4), floats (l&15)*4.
  const float* gsrc = x + (size_t)(rowblk + wloc + (lane >> 4)) * DD + (lane & 15) * 4;

#define STAGE_KT(ktv, bufv)                                                   \
  {                                                                           \
    _Pragma("unroll")                                                         \
    for (int q = 0; q < 4; ++q) {                                             \
      const float* gp = gsrc + (size_t)q * 4 * DD + (ktv) * 64;               \
      float* lp = &xs[(bufv)][wloc + q * 4][0];                               \
      __builtin_amdgcn_global_load_lds(                                       \
          (const __attribute__((address_space(1))) void*)gp,                  \
          (__attribute__((address_space(3))) void*)lp, 16, 0, 0);             \
    }                                                                         \
  }

  // prologue: stage kt = 0 into buf 0 (syncthreads drains vmcnt)
  STAGE_KT(0, 0)
  __syncthreads();

  float acc[16];
#pragma unroll
  for (int i = 0; i < 16; ++i) acc[i] = 0.f;

#pragma unroll 1
  for (int kt = 0; kt < 4; ++kt) {
    const int buf = kt & 1;
    // issue next tile's DMA now; it lands by the end-of-iter barrier
    if (kt < 3) STAGE_KT(kt + 1, buf ^ 1)

    // W working set: identical to the verified round-0 pattern (88 VGPR)
    float wreg[64];
#pragma unroll
    for (int j = 0; j < 64; ++j)
      wreg[j] = W[(size_t)(kt * 64 + j) * UU + lane];

#pragma unroll
    for (int i = 0; i < 16; ++i) {
      const float4* xr4 = (const float4*)&xs[buf][wloc + i][0];  // uniform addr
#pragma unroll
      for (int jv = 0; jv < 16; ++jv) {
        float4 xv = xr4[jv];
        acc[i] = fmaf(xv.x, wreg[jv * 4 + 0], acc[i]);
        acc[i] = fmaf(xv.y, wreg[jv * 4 + 1], acc[i]);
        acc[i] = fmaf(xv.z, wreg[jv * 4 + 2], acc[i]);
        acc[i] = fmaf(xv.w, wreg[jv * 4 + 3], acc[i]);
      }
    }

    // one barrier per kt: drains this iter's DMA (into buf^1) AND ensures
    // every wave finished reading buf before next iter's DMA overwrites it
    __syncthreads();
  }
#undef STAGE_KT

  const float bb = bvec[lane];
  const float lf = left[lane];
  const float rg = right[lane];
#pragma unroll
  for (int i = 0; i < 16; ++i) {
    int r = rbase + i;
    int bidx = r >> 10;          // r / T
    int t = r & (TT - 1);        // r % T
    int len = lengths[bidx];
    float v = acc[i] + bb;
    if (t == 0) v += lf;
    if (t == len - 1) v += rg;
    pot[(size_t)r * UU + lane] = v;
  }
}

// ---------------- forward + viterbi scans ----------------
// 2*B one-wave blocks: [0,B) forward, [B,2B) viterbi. lane = state u.
//
// Forward: scaled linear domain A = exp(alpha - C*ln2). Raw pot ring is 4
// deep (load at t+7), __expf applied 3 steps after the load (covers L2/LLC
// latency) and the result consumed as pcur 3 steps after that. Same
// elements / same op order as before -> bitwise-identical log_norm.
//
// Viterbi FAST path (fast=1): the recurrence only needs max, not argmax.
// Per step: fmaxf trees (fuse to v_max3_f32, ~1.5 inst/elem) and a
// fire-and-forget store of the step's alpha row to valpha[b][t][:].
// Backpointers are recomputed later, massively parallel, in bp_kernel —
// bit-exact (same f32 adds on same bits, exact max, same first-index
// tie-break). SLOW path (fast=0, small workspace): original in-scan
// argmax + bp store + identity tail.
__global__ __launch_bounds__(64)
__attribute__((amdgpu_waves_per_eu(1, 1))) void scan_kernel(
    const float* __restrict__ pot, const float* __restrict__ trans,
    const int* __restrict__ lengths,
    unsigned char* __restrict__ bp, float* __restrict__ log_norm,
    int* __restrict__ last_tag, float* __restrict__ valpha, int fast)
{
  const int lane = threadIdx.x;
  const int b = blockIdx.x & (BB - 1);
  const bool is_vit = blockIdx.x >= BB;
  const int len = lengths[b];
  const float* potb = pot + (size_t)b * TT * UU;

  __shared__ __align__(16) float sh[2][64];

  if (!is_vit) {
    // ---- scaled linear-domain forward
    float tE[64];
#pragma unroll
    for (int v = 0; v < 64; ++v)
      tE[v] = __expf(trans[v * UU + lane]);

    float A = __expf(potb[lane]);          // t = 0; pot ~ N(0,1), safe
    int C = 0;                             // accumulated exponent (ln2 units)

    // pexp ring (exp'd, feeds t+1..t+3) + raw ring (loads for t+3..t+6).
    // Load issued at step t targets element t+7; it is expf'd at step t+4
    // (3 steps of latency cover) and consumed as pcur at step t+7.
    float pe1 = __expf(potb[UU + lane]);
    float pe2 = __expf(potb[2 * UU + lane]);
    float pe3 = __expf(potb[3 * UU + lane]);
    float pr4 = potb[4 * UU + lane];
    float pr5 = potb[5 * UU + lane];
    float pr6 = potb[6 * UU + lane];
    float pr7 = potb[7 * UU + lane];

#pragma unroll 1
    for (int t = 1; t < len; ++t) {
      const int p = t & 1;
      sh[p][lane] = A;
      float pcur = pe1;
      pe1 = pe2; pe2 = pe3;
      pe3 = __expf(pr4);                   // load is 3 steps old: latency covered
      pr4 = pr5; pr5 = pr6; pr6 = pr7;
      int tp = t + 7 < TT ? t + 7 : TT - 1;
      pr7 = potb[(size_t)tp * UU + lane];
      WAVE_LDS_FENCE();                    // write retired before reads
      const float4* sh4 = (const float4*)sh[p];
      float s0 = 0.f, s1 = 0.f, s2 = 0.f, s3 = 0.f;
#pragma unroll
      for (int vg = 0; vg < 4; ++vg) {
        float4 e0 = sh4[vg * 4 + 0];
        float4 e1 = sh4[vg * 4 + 1];
        float4 e2 = sh4[vg * 4 + 2];
        float4 e3 = sh4[vg * 4 + 3];
        s0 = fmaf(e0.x, tE[vg * 16 + 0], s0);
        s0 = fmaf(e0.y, tE[vg * 16 + 1], s0);
        s0 = fmaf(e0.z, tE[vg * 16 + 2], s0);
        s0 = fmaf(e0.w, tE[vg * 16 + 3], s0);
        s1 = fmaf(e1.x, tE[vg * 16 + 4], s1);
        s1 = fmaf(e1.y, tE[vg * 16 + 5], s1);
        s1 = fmaf(e1.z, tE[vg * 16 + 6], s1);
        s1 = fmaf(e1.w, tE[vg * 16 + 7], s1);
        s2 = fmaf(e2.x, tE[vg * 16 + 8], s2);
        s2 = fmaf(e2.y, tE[vg * 16 + 9], s2);
        s2 = fmaf(e2.z, tE[vg * 16 + 10], s2);
        s2 = fmaf(e2.w, tE[vg * 16 + 11], s2);
        s3 = fmaf(e3.x, tE[vg * 16 + 12], s3);
        s3 = fmaf(e3.y, tE[vg * 16 + 13], s3);
        s3 = fmaf(e3.z, tE[vg * 16 + 14], s3);
        s3 = fmaf(e3.w, tE[vg * 16 + 15], s3);
      }
      float sum = (s0 + s1) + (s2 + s3);
      A = sum * pcur;
      if ((t & 3) == 0) {
        // uniform rescale by lane-0 exponent; all-lane values stay in range
        unsigned ab = __builtin_amdgcn_readfirstlane(__float_as_uint(A));
        int k = (int)((ab >> 23) & 0xffu) - 127;
        C += k;
        A = __builtin_ldexpf(A, -k);
      }
    }
    // log_norm[b] = log(sum_lanes A) + C*ln2
    float e = A;
#pragma unroll
    for (int off = 32; off > 0; off >>= 1)
      e += __shfl_xor(e, off);
    if (lane == 0) log_norm[b] = __logf(e) + (float)C * 0.69314718056f;
  } else {
    float tT[64];
#pragma unroll
    for (int v = 0; v < 64; ++v)
      tT[v] = trans[v * UU + lane];

    float va = potb[lane];

    if (fast) {
      // ---- max-only viterbi scan; alphas stored for parallel bp recompute
      float* vab = valpha + (size_t)b * TT * UU;
      vab[lane] = va;                      // row 0 = pot[b,0,:]
      float pn1 = potb[UU + lane];
      float pn2 = potb[2 * UU + lane];
      float pn3 = potb[3 * UU + lane];
      float pn4 = potb[4 * UU + lane];

#pragma unroll 1
      for (int t = 1; t < len; ++t) {
        const int p = t & 1;
        sh[p][lane] = va;
        float pcur = pn1;
        pn1 = pn2; pn2 = pn3; pn3 = pn4;
        int tp = t + 4 < TT ? t + 4 : TT - 1;
        pn4 = potb[(size_t)tp * UU + lane];
        WAVE_LDS_FENCE();
        const float4* sh4 = (const float4*)sh[p];
        // pure max (exact op, tree shape irrelevant); clang fuses nested
        // fmaxf chains to v_max3_f32 -> ~1.5 inst/elem.
        float m0 = -3.4e38f, m1 = -3.4e38f, m2 = -3.4e38f, m3 = -3.4e38f;
#pragma unroll
        for (int vg = 0; vg < 4; ++vg) {
          float4 e0 = sh4[vg * 4 + 0];
          float4 e1 = sh4[vg * 4 + 1];
          float4 e2 = sh4[vg * 4 + 2];
          float4 e3 = sh4[vg * 4 + 3];
          m0 = fmaxf(fmaxf(fmaxf(fmaxf(e0.x + tT[vg * 16 + 0],
                                       e0.y + tT[vg * 16 + 1]),
                                 e0.z + tT[vg * 16 + 2]),
                           e0.w + tT[vg * 16 + 3]), m0);
          m1 = fmaxf(fmaxf(fmaxf(fmaxf(e1.x + tT[vg * 16 + 4],
                                       e1.y + tT[vg * 16 + 5]),
                                 e1.z + tT[vg * 16 + 6]),
                           e1.w + tT[vg * 16 + 7]), m1);
          m2 = fmaxf(fmaxf(fmaxf(fmaxf(e2.x + tT[vg * 16 + 8],
                                       e2.y + tT[vg * 16 + 9]),
                                 e2.z + tT[vg * 16 + 10]),
                           e2.w + tT[vg * 16 + 11]), m2);
          m3 = fmaxf(fmaxf(fmaxf(fmaxf(e3.x + tT[vg * 16 + 12],
                                       e3.y + tT[vg * 16 + 13]),
                                 e3.z + tT[vg * 16 + 14]),
                           e3.w + tT[vg * 16 + 15]), m3);
        }
        float m = fmaxf(fmaxf(m0, m1), fmaxf(m2, m3));
        va = m + pcur;
        vab[(size_t)t * UU + lane] = va;   // fire-and-forget, off-chain
      }
    } else {
      // ---- original in-scan argmax path (fallback for small workspace)
      float pn1 = potb[UU + lane];
      float pn2 = potb[2 * UU + lane];
      float pn3 = potb[3 * UU + lane];
      unsigned char* bpb = bp + (size_t)b * TT * UU;

#pragma unroll 1
      for (int t = 1; t < len; ++t) {
        const int p = t & 1;
        sh[p][lane] = va;
        float pcur = pn1;
        pn1 = pn2; pn2 = pn3;
        int tp = t + 3 < TT ? t + 3 : TT - 1;
        pn3 = potb[(size_t)tp * UU + lane];
        WAVE_LDS_FENCE();
        const float4* sh4 = (const float4*)sh[p];
        float mc[8];
        int ac[8];
#pragma unroll
        for (int c = 0; c < 8; ++c) {
          float m = -3.4e38f;
          int am = 0;
#pragma unroll
          for (int q = 0; q < 2; ++q) {
            float4 a4 = sh4[c * 2 + q];
            int base = c * 8 + q * 4;
            float s;
            s = a4.x + tT[base + 0]; if (s > m) { m = s; am = base + 0; }
            s = a4.y + tT[base + 1]; if (s > m) { m = s; am = base + 1; }
            s = a4.z + tT[base + 2]; if (s > m) { m = s; am = base + 2; }
            s = a4.w + tT[base + 3]; if (s > m) { m = s; am = base + 3; }
          }
          mc[c] = m; ac[c] = am;
        }
        float m = mc[0]; int am = ac[0];
#pragma unroll
        for (int c = 1; c < 8; ++c) {
          if (mc[c] > m) { m = mc[c]; am = ac[c]; }
        }
        va = m + pcur;
        bpb[(size_t)(t - 1) * UU + lane] = (unsigned char)am;
      }

      // identity backpointers for rows r in [len-1, TT-2]
      {
        const int off = lane * 4;          // 0..252
        const unsigned b0 = (unsigned)(off & 63);
        const unsigned pattern = b0 | ((b0 + 1) << 8) | ((b0 + 2) << 16) | ((b0 + 3) << 24);
#pragma unroll 1
        for (int r0 = len - 1; r0 < TT - 1; r0 += 4) {
          int row = r0 + (off >> 6);
          if (row < TT - 1)
            *(unsigned*)(bpb + (size_t)row * UU + (off & 63)) = pattern;
        }
      }
    }

    // last_tag[b] = argmax over lanes, first-index tie-break (np.argmax)
    float v = va;
    int idx = lane;
#pragma unroll
    for (int off = 32; off > 0; off >>= 1) {
      float vo = __shfl_down(v, off);
      int io = __shfl_down(idx, off);
      if (vo > v || (vo == v && io < idx)) { v = vo; idx = io; }
    }
    if (lane == 0) last_tag[b] = idx;
  }
}

// ---------------- parallel backpointer recompute (fast path) ----------------
// bp[b][r][u] = argmax_v(valpha[b][r][v] + trans[v][u]) for r <= len-2,
// identity for r in [len-1, TT-2]. 128*1023 independent rows, one wave per
// 4 rows. Bit-exact vs the serial scan: identical f32 adds on identical
// stored bits, ascending strict-> preserves np.argmax first-index ties.
__global__ __launch_bounds__(256) void bp_kernel(
    const float* __restrict__ valpha, const float* __restrict__ trans,
    const int* __restrict__ lengths, unsigned char* __restrict__ bp)
{
  const int lane = threadIdx.x & 63;
  const int w = __builtin_amdgcn_readfirstlane((int)(threadIdx.x >> 6));
  const int b = blockIdx.x >> 6;                  // 64 blocks per batch elem
  const int rg = ((int)(blockIdx.x & 63)) * 16 + w * 4;
  const int len = lengths[b];

  float tcol[64];
#pragma unroll
  for (int v = 0; v < 64; ++v)
    tcol[v] = trans[v * UU + lane];

  unsigned char* bpb = bp + (size_t)b * TT * UU;
#pragma unroll
  for (int k = 0; k < 4; ++k) {
    int r = rg + k;
    if (r >= TT - 1) continue;
    if (r >= len - 1) {
      bpb[(size_t)r * UU + lane] = (unsigned char)lane;   // identity rows
    } else {
      // valpha row is wave-uniform -> scalar loads (SGPR operand on the add)
      const float* vr = valpha + ((size_t)b * TT + r) * UU;
      float m = vr[0] + tcol[0];
      int am = 0;
#pragma unroll
      for (int v = 1; v < 64; ++v) {
        float s = vr[v] + tcol[v];
        if (s > m) { m = s; am = v; }
      }
      bpb[(size_t)r * UU + lane] = (unsigned char)am;
    }
  }
}

// ---------------- gold score + backtrack + decode ----------------
__global__ __launch_bounds__(64)
__attribute__((amdgpu_waves_per_eu(1, 1))) void decode_kernel(
    const float* __restrict__ pot, const float* __restrict__ trans,
    const int* __restrict__ tags, const int* __restrict__ lengths,
    const unsigned char* __restrict__ bp, const float* __restrict__ log_norm,
    const int* __restrict__ last_tag, float* __restrict__ score,
    float* __restrict__ dec_out)
{
  const int lane = threadIdx.x;
  const int b = blockIdx.x;
  const int len = lengths[b];
  const float* potb = pot + (size_t)b * TT * UU;
  const int* tagb = tags + (size_t)b * TT;

  // gold path score (unary + binary over valid positions)
  float s = 0.f;
#pragma unroll 1
  for (int i = 0; i < TT / 64; ++i) {
    int t = i * 64 + lane;
    if (t < len) {
      int tg = tagb[t];
      s += potb[(size_t)t * UU + tg];
      if (t > 0) s += trans[tagb[t - 1] * UU + tg];
    }
  }
#pragma unroll
  for (int off = 32; off > 0; off >>= 1)
    s += __shfl_xor(s, off);
  if (lane == 0) score[b] = s - log_norm[b];

  // backtrack: row loads are tag-independent -> prefetch 8 deep; only the
  // __shfl is on the dependent chain.
  __shared__ int sd[TT];
  const unsigned char* bpb = bp + (size_t)b * TT * UU;
  int tag = last_tag[b];
  if (lane == 0) sd[TT - 1] = tag;
#pragma unroll 1
  for (int tg = TT - 2; tg >= 0; tg -= 8) {
    unsigned char rows[8];
#pragma unroll
    for (int k = 0; k < 8; ++k) {
      int t = tg - k;
      rows[k] = (t >= 0) ? bpb[(size_t)t * UU + lane] : (unsigned char)0;
    }
#pragma unroll
    for (int k = 0; k < 8; ++k) {
      int t = tg - k;
      if (t >= 0) {
        int prev = __shfl((int)rows[k], tag);
        if (lane == 0) sd[t] = prev;
        tag = prev;
      }
    }
  }
  __syncthreads();
  float* db = dec_out + (size_t)b * TT;
#pragma unroll 1
  for (int i = 0; i < TT / 64; ++i) {
    int t = i * 64 + lane;
    db[t] = (t < len) ? (float)sd[t] : 0.f;
  }
}

// ---------------- final loss reduction ----------------
__global__ __launch_bounds__(128) void loss_kernel(
    const float* __restrict__ score, float* __restrict__ out)
{
  int tid = threadIdx.x;
  float s = score[tid];
#pragma unroll
  for (int off = 32; off > 0; off >>= 1)
    s += __shfl_xor(s, off);
  __shared__ float partial[2];
  if ((tid & 63) == 0) partial[tid >> 6] = s;
  __syncthreads();
  if (tid == 0) out[0] = -(partial[0] + partial[1]) / (float)BB;
}

extern "C" void kernel_launch(void* const* d_in, const int* in_sizes, int n_in,
                              void* d_out, int out_size, void* d_ws, size_t ws_size,
                              hipStream_t stream)
{
  (void)in_sizes; (void)n_in; (void)out_size;
  const float* x      = (const float*)d_in[0];
  const float* W      = (const float*)d_in[1];
  const float* bvec   = (const float*)d_in[2];
  const float* trans  = (const float*)d_in[3];
  const float* left   = (const float*)d_in[4];
  const float* right  = (const float*)d_in[5];
  const int* tags     = (const int*)d_in[6];
  const int* lengths  = (const int*)d_in[7];

  float* out      = (float*)d_out;
  float* dec_out  = out + 1;                       // [B,T] as float
  float* pot      = out + 1 + (size_t)BB * TT;     // [B,T,U]

  const size_t bpB = (size_t)BB * TT * UU;         // 8 MiB backpointers
  const size_t vaB = (size_t)BB * TT * UU * 4;     // 32 MiB viterbi alphas
  const int fast = (ws_size >= bpB + vaB + 4096) ? 1 : 0;

  unsigned char* bp = (unsigned char*)d_ws;
  float* valpha     = (float*)((char*)d_ws + bpB);
  char* tail        = (char*)d_ws + bpB + (fast ? vaB : 0);
  float* log_norm   = (float*)tail;
  int*   last_tag   = (int*)(log_norm + BB);
  float* score      = (float*)(last_tag + BB);

  pot_kernel<<<(BB * TT) / 64, 256, 0, stream>>>(x, W, bvec, left, right, lengths, pot);
  scan_kernel<<<2 * BB, 64, 0, stream>>>(pot, trans, lengths, bp, log_norm, last_tag, valpha, fast);
  if (fast)
    bp_kernel<<<BB * 64, 256, 0, stream>>>(valpha, trans, lengths, bp);
  decode_kernel<<<BB, 64, 0, stream>>>(pot, trans, tags, lengths, bp, log_norm, last_tag, score, dec_out);
  loss_kernel<<<1, 128, 0, stream>>>(score, out);
}

// Round 6
// 833.408 us; speedup vs baseline: 5.2168x; 1.0432x over previous
//
#include <hip/hip_runtime.h>

#define BB 128
#define TT 1024
#define DD 256
#define UU 64

// Single-wave LDS ordering fence (fallback path only).
#define WAVE_LDS_FENCE() asm volatile("s_waitcnt lgkmcnt(0)" ::: "memory")

// ---------------- pot = x @ W + b + boundaries ----------------
// v4 (verified round 5): round-0 register structure (wreg[64] + acc[16])
// with x delivered HBM -> LDS via global_load_lds DMA (width 16): staging
// uses ZERO data registers. LDS layout linear [64][64] (DMA writes
// wave-uniform base + lane*16). Compute reads are wave-uniform ds_read_b128
// broadcasts. Bit-exact: FMA chain d ascending 0..255.
__global__ __launch_bounds__(256) void pot_kernel(
    const float* __restrict__ x, const float* __restrict__ W,
    const float* __restrict__ bvec, const float* __restrict__ left,
    const float* __restrict__ right, const int* __restrict__ lengths,
    float* __restrict__ pot)
{
  const int tid = threadIdx.x;
  const int lane = tid & 63;
  const int w = tid >> 6;
  const int rowblk = (int)blockIdx.x * 64;
  const int wloc = __builtin_amdgcn_readfirstlane(w * 16);  // wave's rows: wloc..wloc+15
  const int rbase = rowblk + wloc;

  // linear, unpadded: required by global_load_lds lane ordering
  __shared__ __align__(16) float xs[2][64][64];

  // Each wave stages its own 16 rows: 4 DMA instructions x (64 lanes x 16 B
  // = 1 KB = 4 rows of 256 B). Lane l covers row +(l>>4), floats (l&15)*4.
  const float* gsrc = x + (size_t)(rowblk + wloc + (lane >> 4)) * DD + (lane & 15) * 4;

#define STAGE_KT(ktv, bufv)                                                   \
  {                                                                           \
    _Pragma("unroll")                                                         \
    for (int q = 0; q < 4; ++q) {                                             \
      const float* gp = gsrc + (size_t)q * 4 * DD + (ktv) * 64;               \
      float* lp = &xs[(bufv)][wloc + q * 4][0];                               \
      __builtin_amdgcn_global_load_lds(                                       \
          (const __attribute__((address_space(1))) void*)gp,                  \
          (__attribute__((address_space(3))) void*)lp, 16, 0, 0);             \
    }                                                                         \
  }

  // prologue: stage kt = 0 into buf 0 (syncthreads drains vmcnt)
  STAGE_KT(0, 0)
  __syncthreads();

  float acc[16];
#pragma unroll
  for (int i = 0; i < 16; ++i) acc[i] = 0.f;

#pragma unroll 1
  for (int kt = 0; kt < 4; ++kt) {
    const int buf = kt & 1;
    // issue next tile's DMA now; it lands by the end-of-iter barrier
    if (kt < 3) STAGE_KT(kt + 1, buf ^ 1)

    // W working set: identical to the verified round-0 pattern
    float wreg[64];
#pragma unroll
    for (int j = 0; j < 64; ++j)
      wreg[j] = W[(size_t)(kt * 64 + j) * UU + lane];

#pragma unroll
    for (int i = 0; i < 16; ++i) {
      const float4* xr4 = (const float4*)&xs[buf][wloc + i][0];  // uniform addr
#pragma unroll
      for (int jv = 0; jv < 16; ++jv) {
        float4 xv = xr4[jv];
        acc[i] = fmaf(xv.x, wreg[jv * 4 + 0], acc[i]);
        acc[i] = fmaf(xv.y, wreg[jv * 4 + 1], acc[i]);
        acc[i] = fmaf(xv.z, wreg[jv * 4 + 2], acc[i]);
        acc[i] = fmaf(xv.w, wreg[jv * 4 + 3], acc[i]);
      }
    }

    // one barrier per kt: drains this iter's DMA (into buf^1) AND ensures
    // every wave finished reading buf before next iter's DMA overwrites it
    __syncthreads();
  }
#undef STAGE_KT

  const float bb = bvec[lane];
  const float lf = left[lane];
  const float rg = right[lane];
#pragma unroll
  for (int i = 0; i < 16; ++i) {
    int r = rbase + i;
    int bidx = r >> 10;          // r / T
    int t = r & (TT - 1);        // r % T
    int len = lengths[bidx];
    float v = acc[i] + bb;
    if (t == 0) v += lf;
    if (t == len - 1) v += rg;
    pot[(size_t)r * UU + lane] = v;
  }
}

// ---------------- forward + viterbi scans ----------------
// 2*B one-wave blocks: [0,B) forward, [B,2B) viterbi. lane = state u.
//
// v5: the per-step 64-vector broadcast is done with v_readlane (VGPR ->
// SGPR -> FMA scalar operand) instead of an LDS write/fence/read round
// trip. One wave per SIMD cannot hide LDS latency (~600+ cycles of the
// measured 875-cycle step); readlane chains are pure issue-bound VALU
// (~256-390 cycles/step). Bit-exact: each partial accumulator receives
// the same values in the same order as the float4-LDS version
// (s0 <- v in {16k+0..3}, k ascending, etc.); fp max is exact.
//
// Forward: scaled linear domain A = exp(alpha - C*ln2); raw pot ring 4
// deep, expf applied 3 steps after load. Viterbi FAST path: max-only
// recurrence + valpha store; backpointers recomputed in bp_kernel.
// SLOW path (small workspace): original LDS argmax scan.
__global__ __launch_bounds__(64)
__attribute__((amdgpu_waves_per_eu(1, 1))) void scan_kernel(
    const float* __restrict__ pot, const float* __restrict__ trans,
    const int* __restrict__ lengths,
    unsigned char* __restrict__ bp, float* __restrict__ log_norm,
    int* __restrict__ last_tag, float* __restrict__ valpha, int fast)
{
  const int lane = threadIdx.x;
  const int b = blockIdx.x & (BB - 1);
  const bool is_vit = blockIdx.x >= BB;
  const int len = lengths[b];
  const float* potb = pot + (size_t)b * TT * UU;

  __shared__ __align__(16) float sh[2][64];   // fallback path only

#define RLF(au, v) __uint_as_float(__builtin_amdgcn_readlane((au), (v)))

  if (!is_vit) {
    // ---- scaled linear-domain forward
    float tE[64];
#pragma unroll
    for (int v = 0; v < 64; ++v)
      tE[v] = __expf(trans[v * UU + lane]);

    float A = __expf(potb[lane]);          // t = 0; pot ~ N(0,1), safe
    int C = 0;                             // accumulated exponent (ln2 units)

    // pexp ring (exp'd, feeds t+1..t+3) + raw ring (loads for t+3..t+6).
    float pe1 = __expf(potb[UU + lane]);
    float pe2 = __expf(potb[2 * UU + lane]);
    float pe3 = __expf(potb[3 * UU + lane]);
    float pr4 = potb[4 * UU + lane];
    float pr5 = potb[5 * UU + lane];
    float pr6 = potb[6 * UU + lane];
    float pr7 = potb[7 * UU + lane];

#pragma unroll 1
    for (int t = 1; t < len; ++t) {
      float pcur = pe1;
      pe1 = pe2; pe2 = pe3;
      pe3 = __expf(pr4);                   // load is 3 steps old: latency covered
      pr4 = pr5; pr5 = pr6; pr6 = pr7;
      int tp = t + 7 < TT ? t + 7 : TT - 1;
      pr7 = potb[(size_t)tp * UU + lane];

      const unsigned Au = __float_as_uint(A);
      float s0 = 0.f, s1 = 0.f, s2 = 0.f, s3 = 0.f;
#pragma unroll
      for (int vg = 0; vg < 4; ++vg) {
#pragma unroll
        for (int c = 0; c < 4; ++c) {
          s0 = fmaf(RLF(Au, vg * 16 + 0 + c),  tE[vg * 16 + 0 + c],  s0);
          s1 = fmaf(RLF(Au, vg * 16 + 4 + c),  tE[vg * 16 + 4 + c],  s1);
          s2 = fmaf(RLF(Au, vg * 16 + 8 + c),  tE[vg * 16 + 8 + c],  s2);
          s3 = fmaf(RLF(Au, vg * 16 + 12 + c), tE[vg * 16 + 12 + c], s3);
        }
      }
      float sum = (s0 + s1) + (s2 + s3);
      A = sum * pcur;
      if ((t & 3) == 0) {
        // uniform rescale by lane-0 exponent; all-lane values stay in range
        unsigned ab = __builtin_amdgcn_readfirstlane(__float_as_uint(A));
        int k = (int)((ab >> 23) & 0xffu) - 127;
        C += k;
        A = __builtin_ldexpf(A, -k);
      }
    }
    // log_norm[b] = log(sum_lanes A) + C*ln2
    float e = A;
#pragma unroll
    for (int off = 32; off > 0; off >>= 1)
      e += __shfl_xor(e, off);
    if (lane == 0) log_norm[b] = __logf(e) + (float)C * 0.69314718056f;
  } else {
    float tT[64];
#pragma unroll
    for (int v = 0; v < 64; ++v)
      tT[v] = trans[v * UU + lane];

    float va = potb[lane];

    if (fast) {
      // ---- max-only viterbi scan (readlane broadcast); alphas stored for
      // parallel bp recompute
      float* vab = valpha + (size_t)b * TT * UU;
      vab[lane] = va;                      // row 0 = pot[b,0,:]
      float pn1 = potb[UU + lane];
      float pn2 = potb[2 * UU + lane];
      float pn3 = potb[3 * UU + lane];
      float pn4 = potb[4 * UU + lane];

#pragma unroll 1
      for (int t = 1; t < len; ++t) {
        float pcur = pn1;
        pn1 = pn2; pn2 = pn3; pn3 = pn4;
        int tp = t + 4 < TT ? t + 4 : TT - 1;
        pn4 = potb[(size_t)tp * UU + lane];

        const unsigned Vu = __float_as_uint(va);
        float m0 = -3.4e38f, m1 = -3.4e38f, m2 = -3.4e38f, m3 = -3.4e38f;
#pragma unroll
        for (int vg = 0; vg < 4; ++vg) {
          m0 = fmaxf(fmaxf(fmaxf(fmaxf(
                   RLF(Vu, vg * 16 + 0) + tT[vg * 16 + 0],
                   RLF(Vu, vg * 16 + 1) + tT[vg * 16 + 1]),
                   RLF(Vu, vg * 16 + 2) + tT[vg * 16 + 2]),
                   RLF(Vu, vg * 16 + 3) + tT[vg * 16 + 3]), m0);
          m1 = fmaxf(fmaxf(fmaxf(fmaxf(
                   RLF(Vu, vg * 16 + 4) + tT[vg * 16 + 4],
                   RLF(Vu, vg * 16 + 5) + tT[vg * 16 + 5]),
                   RLF(Vu, vg * 16 + 6) + tT[vg * 16 + 6]),
                   RLF(Vu, vg * 16 + 7) + tT[vg * 16 + 7]), m1);
          m2 = fmaxf(fmaxf(fmaxf(fmaxf(
                   RLF(Vu, vg * 16 + 8) + tT[vg * 16 + 8],
                   RLF(Vu, vg * 16 + 9) + tT[vg * 16 + 9]),
                   RLF(Vu, vg * 16 + 10) + tT[vg * 16 + 10]),
                   RLF(Vu, vg * 16 + 11) + tT[vg * 16 + 11]), m2);
          m3 = fmaxf(fmaxf(fmaxf(fmaxf(
                   RLF(Vu, vg * 16 + 12) + tT[vg * 16 + 12],
                   RLF(Vu, vg * 16 + 13) + tT[vg * 16 + 13]),
                   RLF(Vu, vg * 16 + 14) + tT[vg * 16 + 14]),
                   RLF(Vu, vg * 16 + 15) + tT[vg * 16 + 15]), m3);
        }
        float m = fmaxf(fmaxf(m0, m1), fmaxf(m2, m3));
        va = m + pcur;
        vab[(size_t)t * UU + lane] = va;   // fire-and-forget, off-chain
      }
    } else {
      // ---- original in-scan argmax path (fallback for small workspace)
      float pn1 = potb[UU + lane];
      float pn2 = potb[2 * UU + lane];
      float pn3 = potb[3 * UU + lane];
      unsigned char* bpb = bp + (size_t)b * TT * UU;

#pragma unroll 1
      for (int t = 1; t < len; ++t) {
        const int p = t & 1;
        sh[p][lane] = va;
        float pcur = pn1;
        pn1 = pn2; pn2 = pn3;
        int tp = t + 3 < TT ? t + 3 : TT - 1;
        pn3 = potb[(size_t)tp * UU + lane];
        WAVE_LDS_FENCE();
        const float4* sh4 = (const float4*)sh[p];
        float mc[8];
        int ac[8];
#pragma unroll
        for (int c = 0; c < 8; ++c) {
          float m = -3.4e38f;
          int am = 0;
#pragma unroll
          for (int q = 0; q < 2; ++q) {
            float4 a4 = sh4[c * 2 + q];
            int base = c * 8 + q * 4;
            float s;
            s = a4.x + tT[base + 0]; if (s > m) { m = s; am = base + 0; }
            s = a4.y + tT[base + 1]; if (s > m) { m = s; am = base + 1; }
            s = a4.z + tT[base + 2]; if (s > m) { m = s; am = base + 2; }
            s = a4.w + tT[base + 3]; if (s > m) { m = s; am = base + 3; }
          }
          mc[c] = m; ac[c] = am;
        }
        float m = mc[0]; int am = ac[0];
#pragma unroll
        for (int c = 1; c < 8; ++c) {
          if (mc[c] > m) { m = mc[c]; am = ac[c]; }
        }
        va = m + pcur;
        bpb[(size_t)(t - 1) * UU + lane] = (unsigned char)am;
      }

      // identity backpointers for rows r in [len-1, TT-2]
      {
        const int off = lane * 4;          // 0..252
        const unsigned b0 = (unsigned)(off & 63);
        const unsigned pattern = b0 | ((b0 + 1) << 8) | ((b0 + 2) << 16) | ((b0 + 3) << 24);
#pragma unroll 1
        for (int r0 = len - 1; r0 < TT - 1; r0 += 4) {
          int row = r0 + (off >> 6);
          if (row < TT - 1)
            *(unsigned*)(bpb + (size_t)row * UU + (off & 63)) = pattern;
        }
      }
    }

    // last_tag[b] = argmax over lanes, first-index tie-break (np.argmax)
    float v = va;
    int idx = lane;
#pragma unroll
    for (int off = 32; off > 0; off >>= 1) {
      float vo = __shfl_down(v, off);
      int io = __shfl_down(idx, off);
      if (vo > v || (vo == v && io < idx)) { v = vo; idx = io; }
    }
    if (lane == 0) last_tag[b] = idx;
  }
#undef RLF
}

// ---------------- parallel backpointer recompute (fast path) ----------------
// bp[b][r][u] = argmax_v(valpha[b][r][v] + trans[v][u]) for r <= len-2,
// identity for r in [len-1, TT-2]. 128*1023 independent rows, one wave per
// 4 rows. Bit-exact vs the serial scan: identical f32 adds on identical
// stored bits, ascending strict-> preserves np.argmax first-index ties.
__global__ __launch_bounds__(256) void bp_kernel(
    const float* __restrict__ valpha, const float* __restrict__ trans,
    const int* __restrict__ lengths, unsigned char* __restrict__ bp)
{
  const int lane = threadIdx.x & 63;
  const int w = __builtin_amdgcn_readfirstlane((int)(threadIdx.x >> 6));
  const int b = blockIdx.x >> 6;                  // 64 blocks per batch elem
  const int rg = ((int)(blockIdx.x & 63)) * 16 + w * 4;
  const int len = lengths[b];

  float tcol[64];
#pragma unroll
  for (int v = 0; v < 64; ++v)
    tcol[v] = trans[v * UU + lane];

  unsigned char* bpb = bp + (size_t)b * TT * UU;
#pragma unroll
  for (int k = 0; k < 4; ++k) {
    int r = rg + k;
    if (r >= TT - 1) continue;
    if (r >= len - 1) {
      bpb[(size_t)r * UU + lane] = (unsigned char)lane;   // identity rows
    } else {
      // valpha row is wave-uniform -> scalar loads (SGPR operand on the add)
      const float* vr = valpha + ((size_t)b * TT + r) * UU;
      float m = vr[0] + tcol[0];
      int am = 0;
#pragma unroll
      for (int v = 1; v < 64; ++v) {
        float s = vr[v] + tcol[v];
        if (s > m) { m = s; am = v; }
      }
      bpb[(size_t)r * UU + lane] = (unsigned char)am;
    }
  }
}

// ---------------- gold score + backtrack + decode ----------------
__global__ __launch_bounds__(64)
__attribute__((amdgpu_waves_per_eu(1, 1))) void decode_kernel(
    const float* __restrict__ pot, const float* __restrict__ trans,
    const int* __restrict__ tags, const int* __restrict__ lengths,
    const unsigned char* __restrict__ bp, const float* __restrict__ log_norm,
    const int* __restrict__ last_tag, float* __restrict__ score,
    float* __restrict__ dec_out)
{
  const int lane = threadIdx.x;
  const int b = blockIdx.x;
  const int len = lengths[b];
  const float* potb = pot + (size_t)b * TT * UU;
  const int* tagb = tags + (size_t)b * TT;

  // gold path score (unary + binary over valid positions)
  float s = 0.f;
#pragma unroll 1
  for (int i = 0; i < TT / 64; ++i) {
    int t = i * 64 + lane;
    if (t < len) {
      int tg = tagb[t];
      s += potb[(size_t)t * UU + tg];
      if (t > 0) s += trans[tagb[t - 1] * UU + tg];
    }
  }
#pragma unroll
  for (int off = 32; off > 0; off >>= 1)
    s += __shfl_xor(s, off);
  if (lane == 0) score[b] = s - log_norm[b];

  // backtrack: row loads are tag-independent -> prefetch 8 deep; only the
  // __shfl is on the dependent chain.
  __shared__ int sd[TT];
  const unsigned char* bpb = bp + (size_t)b * TT * UU;
  int tag = last_tag[b];
  if (lane == 0) sd[TT - 1] = tag;
#pragma unroll 1
  for (int tg = TT - 2; tg >= 0; tg -= 8) {
    unsigned char rows[8];
#pragma unroll
    for (int k = 0; k < 8; ++k) {
      int t = tg - k;
      rows[k] = (t >= 0) ? bpb[(size_t)t * UU + lane] : (unsigned char)0;
    }
#pragma unroll
    for (int k = 0; k < 8; ++k) {
      int t = tg - k;
      if (t >= 0) {
        int prev = __shfl((int)rows[k], tag);
        if (lane == 0) sd[t] = prev;
        tag = prev;
      }
    }
  }
  __syncthreads();
  float* db = dec_out + (size_t)b * TT;
#pragma unroll 1
  for (int i = 0; i < TT / 64; ++i) {
    int t = i * 64 + lane;
    db[t] = (t < len) ? (float)sd[t] : 0.f;
  }
}

// ---------------- final loss reduction ----------------
__global__ __launch_bounds__(128) void loss_kernel(
    const float* __restrict__ score, float* __restrict__ out)
{
  int tid = threadIdx.x;
  float s = score[tid];
#pragma unroll
  for (int off = 32; off > 0; off >>= 1)
    s += __shfl_xor(s, off);
  __shared__ float partial[2];
  if ((tid & 63) == 0) partial[tid >> 6] = s;
  __syncthreads();
  if (tid == 0) out[0] = -(partial[0] + partial[1]) / (float)BB;
}

extern "C" void kernel_launch(void* const* d_in, const int* in_sizes, int n_in,
                              void* d_out, int out_size, void* d_ws, size_t ws_size,
                              hipStream_t stream)
{
  (void)in_sizes; (void)n_in; (void)out_size;
  const float* x      = (const float*)d_in[0];
  const float* W      = (const float*)d_in[1];
  const float* bvec   = (const float*)d_in[2];
  const float* trans  = (const float*)d_in[3];
  const float* left   = (const float*)d_in[4];
  const float* right  = (const float*)d_in[5];
  const int* tags     = (const int*)d_in[6];
  const int* lengths  = (const int*)d_in[7];

  float* out      = (float*)d_out;
  float* dec_out  = out + 1;                       // [B,T] as float
  float* pot      = out + 1 + (size_t)BB * TT;     // [B,T,U]

  const size_t bpB = (size_t)BB * TT * UU;         // 8 MiB backpointers
  const size_t vaB = (size_t)BB * TT * UU * 4;     // 32 MiB viterbi alphas
  const int fast = (ws_size >= bpB + vaB + 4096) ? 1 : 0;

  unsigned char* bp = (unsigned char*)d_ws;
  float* valpha     = (float*)((char*)d_ws + bpB);
  char* tail        = (char*)d_ws + bpB + (fast ? vaB : 0);
  float* log_norm   = (float*)tail;
  int*   last_tag   = (int*)(log_norm + BB);
  float* score      = (float*)(last_tag + BB);

  pot_kernel<<<(BB * TT) / 64, 256, 0, stream>>>(x, W, bvec, left, right, lengths, pot);
  scan_kernel<<<2 * BB, 64, 0, stream>>>(pot, trans, lengths, bp, log_norm, last_tag, valpha, fast);
  if (fast)
    bp_kernel<<<BB * 64, 256, 0, stream>>>(valpha, trans, lengths, bp);
  decode_kernel<<<BB, 64, 0, stream>>>(pot, trans, tags, lengths, bp, log_norm, last_tag, score, dec_out);
  loss_kernel<<<1, 128, 0, stream>>>(score, out);
}

// Round 7
// 828.163 us; speedup vs baseline: 5.2499x; 1.0063x over previous
//
#include <hip/hip_runtime.h>

#define BB 128
#define TT 1024
#define DD 256
#define UU 64

// Single-wave LDS ordering fence (fallback path only).
#define WAVE_LDS_FENCE() asm volatile("s_waitcnt lgkmcnt(0)" ::: "memory")

// ---------------- pot = x @ W + b + boundaries ----------------
// v4 (verified round 5): round-0 register structure (wreg[64] + acc[16])
// with x delivered HBM -> LDS via global_load_lds DMA (width 16): staging
// uses ZERO data registers. LDS layout linear [64][64] (DMA writes
// wave-uniform base + lane*16). Compute reads are wave-uniform ds_read_b128
// broadcasts. Bit-exact: FMA chain d ascending 0..255.
__global__ __launch_bounds__(256) void pot_kernel(
    const float* __restrict__ x, const float* __restrict__ W,
    const float* __restrict__ bvec, const float* __restrict__ left,
    const float* __restrict__ right, const int* __restrict__ lengths,
    float* __restrict__ pot)
{
  const int tid = threadIdx.x;
  const int lane = tid & 63;
  const int w = tid >> 6;
  const int rowblk = (int)blockIdx.x * 64;
  const int wloc = __builtin_amdgcn_readfirstlane(w * 16);  // wave's rows: wloc..wloc+15
  const int rbase = rowblk + wloc;

  // linear, unpadded: required by global_load_lds lane ordering
  __shared__ __align__(16) float xs[2][64][64];

  // Each wave stages its own 16 rows: 4 DMA instructions x (64 lanes x 16 B
  // = 1 KB = 4 rows of 256 B). Lane l covers row +(l>>4), floats (l&15)*4.
  const float* gsrc = x + (size_t)(rowblk + wloc + (lane >> 4)) * DD + (lane & 15) * 4;

#define STAGE_KT(ktv, bufv)                                                   \
  {                                                                           \
    _Pragma("unroll")                                                         \
    for (int q = 0; q < 4; ++q) {                                             \
      const float* gp = gsrc + (size_t)q * 4 * DD + (ktv) * 64;               \
      float* lp = &xs[(bufv)][wloc + q * 4][0];                               \
      __builtin_amdgcn_global_load_lds(                                       \
          (const __attribute__((address_space(1))) void*)gp,                  \
          (__attribute__((address_space(3))) void*)lp, 16, 0, 0);             \
    }                                                                         \
  }

  // prologue: stage kt = 0 into buf 0 (syncthreads drains vmcnt)
  STAGE_KT(0, 0)
  __syncthreads();

  float acc[16];
#pragma unroll
  for (int i = 0; i < 16; ++i) acc[i] = 0.f;

#pragma unroll 1
  for (int kt = 0; kt < 4; ++kt) {
    const int buf = kt & 1;
    // issue next tile's DMA now; it lands by the end-of-iter barrier
    if (kt < 3) STAGE_KT(kt + 1, buf ^ 1)

    // W working set: identical to the verified round-0 pattern
    float wreg[64];
#pragma unroll
    for (int j = 0; j < 64; ++j)
      wreg[j] = W[(size_t)(kt * 64 + j) * UU + lane];

#pragma unroll
    for (int i = 0; i < 16; ++i) {
      const float4* xr4 = (const float4*)&xs[buf][wloc + i][0];  // uniform addr
#pragma unroll
      for (int jv = 0; jv < 16; ++jv) {
        float4 xv = xr4[jv];
        acc[i] = fmaf(xv.x, wreg[jv * 4 + 0], acc[i]);
        acc[i] = fmaf(xv.y, wreg[jv * 4 + 1], acc[i]);
        acc[i] = fmaf(xv.z, wreg[jv * 4 + 2], acc[i]);
        acc[i] = fmaf(xv.w, wreg[jv * 4 + 3], acc[i]);
      }
    }

    // one barrier per kt: drains this iter's DMA (into buf^1) AND ensures
    // every wave finished reading buf before next iter's DMA overwrites it
    __syncthreads();
  }
#undef STAGE_KT

  const float bb = bvec[lane];
  const float lf = left[lane];
  const float rg = right[lane];
#pragma unroll
  for (int i = 0; i < 16; ++i) {
    int r = rbase + i;
    int bidx = r >> 10;          // r / T
    int t = r & (TT - 1);        // r % T
    int len = lengths[bidx];
    float v = acc[i] + bb;
    if (t == 0) v += lf;
    if (t == len - 1) v += rg;
    pot[(size_t)r * UU + lane] = v;
  }
}

// ---------------- forward + viterbi scans ----------------
// 2*B one-wave blocks: [0,B) forward, [B,2B) viterbi. lane = state u.
//
// v6: readlane broadcasts BATCHED 16 at a time into statically-indexed
// locals (uniform values -> SGPRs), with sched_barrier(0) pinning the
// readlane batch before the consuming FMA/max batch. Round-6 measured
// ~775 cy/step at ~200 VALU issued (~52% of one SIMD's cycles): the
// remaining stall is the VALU-writes-SGPR -> VALU-reads-SGPR hazard paid
// on every interleaved readlane;fma pair. Batching gives each readlane
// 15 instructions of separation before its consumer -> hazard hidden.
// Bit-exact: per-accumulator value order unchanged (s0 <- vg*16+{0..3}
// ascending, etc.; identical fmax trees).
//
// Forward: scaled linear domain A = exp(alpha - C*ln2); raw pot ring 4
// deep, expf applied 3 steps after load. Viterbi FAST path: max-only
// recurrence + valpha store; backpointers recomputed in bp_kernel.
// SLOW path (small workspace): original LDS argmax scan.
__global__ __launch_bounds__(64)
__attribute__((amdgpu_waves_per_eu(1, 1))) void scan_kernel(
    const float* __restrict__ pot, const float* __restrict__ trans,
    const int* __restrict__ lengths,
    unsigned char* __restrict__ bp, float* __restrict__ log_norm,
    int* __restrict__ last_tag, float* __restrict__ valpha, int fast)
{
  const int lane = threadIdx.x;
  const int b = blockIdx.x & (BB - 1);
  const bool is_vit = blockIdx.x >= BB;
  const int len = lengths[b];
  const float* potb = pot + (size_t)b * TT * UU;

  __shared__ __align__(16) float sh[2][64];   // fallback path only

#define RLF(au, v) __uint_as_float(__builtin_amdgcn_readlane((au), (v)))

  if (!is_vit) {
    // ---- scaled linear-domain forward
    float tE[64];
#pragma unroll
    for (int v = 0; v < 64; ++v)
      tE[v] = __expf(trans[v * UU + lane]);

    float A = __expf(potb[lane]);          // t = 0; pot ~ N(0,1), safe
    int C = 0;                             // accumulated exponent (ln2 units)

    // pexp ring (exp'd, feeds t+1..t+3) + raw ring (loads for t+3..t+6).
    float pe1 = __expf(potb[UU + lane]);
    float pe2 = __expf(potb[2 * UU + lane]);
    float pe3 = __expf(potb[3 * UU + lane]);
    float pr4 = potb[4 * UU + lane];
    float pr5 = potb[5 * UU + lane];
    float pr6 = potb[6 * UU + lane];
    float pr7 = potb[7 * UU + lane];

#pragma unroll 1
    for (int t = 1; t < len; ++t) {
      float pcur = pe1;
      pe1 = pe2; pe2 = pe3;
      pe3 = __expf(pr4);                   // load is 3 steps old: latency covered
      pr4 = pr5; pr5 = pr6; pr6 = pr7;
      int tp = t + 7 < TT ? t + 7 : TT - 1;
      pr7 = potb[(size_t)tp * UU + lane];

      const unsigned Au = __float_as_uint(A);
      float s0 = 0.f, s1 = 0.f, s2 = 0.f, s3 = 0.f;
#pragma unroll
      for (int vg = 0; vg < 4; ++vg) {
        float bc[16];
#pragma unroll
        for (int c = 0; c < 16; ++c)
          bc[c] = RLF(Au, vg * 16 + c);
        __builtin_amdgcn_sched_barrier(0);  // all 16 readlanes precede uses
#pragma unroll
        for (int c = 0; c < 4; ++c) {
          s0 = fmaf(bc[c],      tE[vg * 16 + 0 + c],  s0);
          s1 = fmaf(bc[4 + c],  tE[vg * 16 + 4 + c],  s1);
          s2 = fmaf(bc[8 + c],  tE[vg * 16 + 8 + c],  s2);
          s3 = fmaf(bc[12 + c], tE[vg * 16 + 12 + c], s3);
        }
      }
      float sum = (s0 + s1) + (s2 + s3);
      A = sum * pcur;
      if ((t & 3) == 0) {
        // uniform rescale by lane-0 exponent; all-lane values stay in range
        unsigned ab = __builtin_amdgcn_readfirstlane(__float_as_uint(A));
        int k = (int)((ab >> 23) & 0xffu) - 127;
        C += k;
        A = __builtin_ldexpf(A, -k);
      }
    }
    // log_norm[b] = log(sum_lanes A) + C*ln2
    float e = A;
#pragma unroll
    for (int off = 32; off > 0; off >>= 1)
      e += __shfl_xor(e, off);
    if (lane == 0) log_norm[b] = __logf(e) + (float)C * 0.69314718056f;
  } else {
    float tT[64];
#pragma unroll
    for (int v = 0; v < 64; ++v)
      tT[v] = trans[v * UU + lane];

    float va = potb[lane];

    if (fast) {
      // ---- max-only viterbi scan (batched readlane broadcast); alphas
      // stored for parallel bp recompute
      float* vab = valpha + (size_t)b * TT * UU;
      vab[lane] = va;                      // row 0 = pot[b,0,:]
      float pn1 = potb[UU + lane];
      float pn2 = potb[2 * UU + lane];
      float pn3 = potb[3 * UU + lane];
      float pn4 = potb[4 * UU + lane];

#pragma unroll 1
      for (int t = 1; t < len; ++t) {
        float pcur = pn1;
        pn1 = pn2; pn2 = pn3; pn3 = pn4;
        int tp = t + 4 < TT ? t + 4 : TT - 1;
        pn4 = potb[(size_t)tp * UU + lane];

        const unsigned Vu = __float_as_uint(va);
        float m0 = -3.4e38f, m1 = -3.4e38f, m2 = -3.4e38f, m3 = -3.4e38f;
#pragma unroll
        for (int vg = 0; vg < 4; ++vg) {
          float bc[16];
#pragma unroll
          for (int c = 0; c < 16; ++c)
            bc[c] = RLF(Vu, vg * 16 + c);
          __builtin_amdgcn_sched_barrier(0);
          m0 = fmaxf(fmaxf(fmaxf(fmaxf(
                   bc[0] + tT[vg * 16 + 0],
                   bc[1] + tT[vg * 16 + 1]),
                   bc[2] + tT[vg * 16 + 2]),
                   bc[3] + tT[vg * 16 + 3]), m0);
          m1 = fmaxf(fmaxf(fmaxf(fmaxf(
                   bc[4] + tT[vg * 16 + 4],
                   bc[5] + tT[vg * 16 + 5]),
                   bc[6] + tT[vg * 16 + 6]),
                   bc[7] + tT[vg * 16 + 7]), m1);
          m2 = fmaxf(fmaxf(fmaxf(fmaxf(
                   bc[8] + tT[vg * 16 + 8],
                   bc[9] + tT[vg * 16 + 9]),
                   bc[10] + tT[vg * 16 + 10]),
                   bc[11] + tT[vg * 16 + 11]), m2);
          m3 = fmaxf(fmaxf(fmaxf(fmaxf(
                   bc[12] + tT[vg * 16 + 12],
                   bc[13] + tT[vg * 16 + 13]),
                   bc[14] + tT[vg * 16 + 14]),
                   bc[15] + tT[vg * 16 + 15]), m3);
        }
        float m = fmaxf(fmaxf(m0, m1), fmaxf(m2, m3));
        va = m + pcur;
        vab[(size_t)t * UU + lane] = va;   // fire-and-forget, off-chain
      }
    } else {
      // ---- original in-scan argmax path (fallback for small workspace)
      float pn1 = potb[UU + lane];
      float pn2 = potb[2 * UU + lane];
      float pn3 = potb[3 * UU + lane];
      unsigned char* bpb = bp + (size_t)b * TT * UU;

#pragma unroll 1
      for (int t = 1; t < len; ++t) {
        const int p = t & 1;
        sh[p][lane] = va;
        float pcur = pn1;
        pn1 = pn2; pn2 = pn3;
        int tp = t + 3 < TT ? t + 3 : TT - 1;
        pn3 = potb[(size_t)tp * UU + lane];
        WAVE_LDS_FENCE();
        const float4* sh4 = (const float4*)sh[p];
        float mc[8];
        int ac[8];
#pragma unroll
        for (int c = 0; c < 8; ++c) {
          float m = -3.4e38f;
          int am = 0;
#pragma unroll
          for (int q = 0; q < 2; ++q) {
            float4 a4 = sh4[c * 2 + q];
            int base = c * 8 + q * 4;
            float s;
            s = a4.x + tT[base + 0]; if (s > m) { m = s; am = base + 0; }
            s = a4.y + tT[base + 1]; if (s > m) { m = s; am = base + 1; }
            s = a4.z + tT[base + 2]; if (s > m) { m = s; am = base + 2; }
            s = a4.w + tT[base + 3]; if (s > m) { m = s; am = base + 3; }
          }
          mc[c] = m; ac[c] = am;
        }
        float m = mc[0]; int am = ac[0];
#pragma unroll
        for (int c = 1; c < 8; ++c) {
          if (mc[c] > m) { m = mc[c]; am = ac[c]; }
        }
        va = m + pcur;
        bpb[(size_t)(t - 1) * UU + lane] = (unsigned char)am;
      }

      // identity backpointers for rows r in [len-1, TT-2]
      {
        const int off = lane * 4;          // 0..252
        const unsigned b0 = (unsigned)(off & 63);
        const unsigned pattern = b0 | ((b0 + 1) << 8) | ((b0 + 2) << 16) | ((b0 + 3) << 24);
#pragma unroll 1
        for (int r0 = len - 1; r0 < TT - 1; r0 += 4) {
          int row = r0 + (off >> 6);
          if (row < TT - 1)
            *(unsigned*)(bpb + (size_t)row * UU + (off & 63)) = pattern;
        }
      }
    }

    // last_tag[b] = argmax over lanes, first-index tie-break (np.argmax)
    float v = va;
    int idx = lane;
#pragma unroll
    for (int off = 32; off > 0; off >>= 1) {
      float vo = __shfl_down(v, off);
      int io = __shfl_down(idx, off);
      if (vo > v || (vo == v && io < idx)) { v = vo; idx = io; }
    }
    if (lane == 0) last_tag[b] = idx;
  }
#undef RLF
}

// ---------------- parallel backpointer recompute (fast path) ----------------
// bp[b][r][u] = argmax_v(valpha[b][r][v] + trans[v][u]) for r <= len-2,
// identity for r in [len-1, TT-2]. 128*1023 independent rows, one wave per
// 4 rows. Bit-exact vs the serial scan: identical f32 adds on identical
// stored bits, ascending strict-> preserves np.argmax first-index ties.
__global__ __launch_bounds__(256) void bp_kernel(
    const float* __restrict__ valpha, const float* __restrict__ trans,
    const int* __restrict__ lengths, unsigned char* __restrict__ bp)
{
  const int lane = threadIdx.x & 63;
  const int w = __builtin_amdgcn_readfirstlane((int)(threadIdx.x >> 6));
  const int b = blockIdx.x >> 6;                  // 64 blocks per batch elem
  const int rg = ((int)(blockIdx.x & 63)) * 16 + w * 4;
  const int len = lengths[b];

  float tcol[64];
#pragma unroll
  for (int v = 0; v < 64; ++v)
    tcol[v] = trans[v * UU + lane];

  unsigned char* bpb = bp + (size_t)b * TT * UU;
#pragma unroll
  for (int k = 0; k < 4; ++k) {
    int r = rg + k;
    if (r >= TT - 1) continue;
    if (r >= len - 1) {
      bpb[(size_t)r * UU + lane] = (unsigned char)lane;   // identity rows
    } else {
      // valpha row is wave-uniform -> scalar loads (SGPR operand on the add)
      const float* vr = valpha + ((size_t)b * TT + r) * UU;
      float m = vr[0] + tcol[0];
      int am = 0;
#pragma unroll
      for (int v = 1; v < 64; ++v) {
        float s = vr[v] + tcol[v];
        if (s > m) { m = s; am = v; }
      }
      bpb[(size_t)r * UU + lane] = (unsigned char)am;
    }
  }
}

// ---------------- gold score + backtrack + decode ----------------
__global__ __launch_bounds__(64)
__attribute__((amdgpu_waves_per_eu(1, 1))) void decode_kernel(
    const float* __restrict__ pot, const float* __restrict__ trans,
    const int* __restrict__ tags, const int* __restrict__ lengths,
    const unsigned char* __restrict__ bp, const float* __restrict__ log_norm,
    const int* __restrict__ last_tag, float* __restrict__ score,
    float* __restrict__ dec_out)
{
  const int lane = threadIdx.x;
  const int b = blockIdx.x;
  const int len = lengths[b];
  const float* potb = pot + (size_t)b * TT * UU;
  const int* tagb = tags + (size_t)b * TT;

  // gold path score (unary + binary over valid positions)
  float s = 0.f;
#pragma unroll 1
  for (int i = 0; i < TT / 64; ++i) {
    int t = i * 64 + lane;
    if (t < len) {
      int tg = tagb[t];
      s += potb[(size_t)t * UU + tg];
      if (t > 0) s += trans[tagb[t - 1] * UU + tg];
    }
  }
#pragma unroll
  for (int off = 32; off > 0; off >>= 1)
    s += __shfl_xor(s, off);
  if (lane == 0) score[b] = s - log_norm[b];

  // backtrack: row loads are tag-independent -> prefetch 8 deep; only the
  // __shfl is on the dependent chain.
  __shared__ int sd[TT];
  const unsigned char* bpb = bp + (size_t)b * TT * UU;
  int tag = last_tag[b];
  if (lane == 0) sd[TT - 1] = tag;
#pragma unroll 1
  for (int tg = TT - 2; tg >= 0; tg -= 8) {
    unsigned char rows[8];
#pragma unroll
    for (int k = 0; k < 8; ++k) {
      int t = tg - k;
      rows[k] = (t >= 0) ? bpb[(size_t)t * UU + lane] : (unsigned char)0;
    }
#pragma unroll
    for (int k = 0; k < 8; ++k) {
      int t = tg - k;
      if (t >= 0) {
        int prev = __shfl((int)rows[k], tag);
        if (lane == 0) sd[t] = prev;
        tag = prev;
      }
    }
  }
  __syncthreads();
  float* db = dec_out + (size_t)b * TT;
#pragma unroll 1
  for (int i = 0; i < TT / 64; ++i) {
    int t = i * 64 + lane;
    db[t] = (t < len) ? (float)sd[t] : 0.f;
  }
}

// ---------------- final loss reduction ----------------
__global__ __launch_bounds__(128) void loss_kernel(
    const float* __restrict__ score, float* __restrict__ out)
{
  int tid = threadIdx.x;
  float s = score[tid];
#pragma unroll
  for (int off = 32; off > 0; off >>= 1)
    s += __shfl_xor(s, off);
  __shared__ float partial[2];
  if ((tid & 63) == 0) partial[tid >> 6] = s;
  __syncthreads();
  if (tid == 0) out[0] = -(partial[0] + partial[1]) / (float)BB;
}

extern "C" void kernel_launch(void* const* d_in, const int* in_sizes, int n_in,
                              void* d_out, int out_size, void* d_ws, size_t ws_size,
                              hipStream_t stream)
{
  (void)in_sizes; (void)n_in; (void)out_size;
  const float* x      = (const float*)d_in[0];
  const float* W      = (const float*)d_in[1];
  const float* bvec   = (const float*)d_in[2];
  const float* trans  = (const float*)d_in[3];
  const float* left   = (const float*)d_in[4];
  const float* right  = (const float*)d_in[5];
  const int* tags     = (const int*)d_in[6];
  const int* lengths  = (const int*)d_in[7];

  float* out      = (float*)d_out;
  float* dec_out  = out + 1;                       // [B,T] as float
  float* pot      = out + 1 + (size_t)BB * TT;     // [B,T,U]

  const size_t bpB = (size_t)BB * TT * UU;         // 8 MiB backpointers
  const size_t vaB = (size_t)BB * TT * UU * 4;     // 32 MiB viterbi alphas
  const int fast = (ws_size >= bpB + vaB + 4096) ? 1 : 0;

  unsigned char* bp = (unsigned char*)d_ws;
  float* valpha     = (float*)((char*)d_ws + bpB);
  char* tail        = (char*)d_ws + bpB + (fast ? vaB : 0);
  float* log_norm   = (float*)tail;
  int*   last_tag   = (int*)(log_norm + BB);
  float* score      = (float*)(last_tag + BB);

  pot_kernel<<<(BB * TT) / 64, 256, 0, stream>>>(x, W, bvec, left, right, lengths, pot);
  scan_kernel<<<2 * BB, 64, 0, stream>>>(pot, trans, lengths, bp, log_norm, last_tag, valpha, fast);
  if (fast)
    bp_kernel<<<BB * 64, 256, 0, stream>>>(valpha, trans, lengths, bp);
  decode_kernel<<<BB, 64, 0, stream>>>(pot, trans, tags, lengths, bp, log_norm, last_tag, score, dec_out);
  loss_kernel<<<1, 128, 0, stream>>>(score, out);
}